// Round 17
// baseline (260.498 us; speedup 1.0000x reference)
//
#include <hip/hip_runtime.h>
#include <hip/hip_bf16.h>

#define USER_NUM 50000
#define ITEM_NUM 20000
#define NNODE    70000
#define DD       64
#define CHUNK    1024
#define NCHUNK   ((NNODE + CHUNK - 1) / CHUNK)   // 69
#define GROWS    (NNODE / 8)                     // 8750 rows per coarse group
#define APB      2048                            // append: edges per block
#define EPT      8                               // append: edges per thread
#define NS2      128                             // scatter2 stripes per group
#define NB3      16                              // hist3 blocks per group
#define T_CAP    32768                           // max touched slots (B=16384)
#define NCHUNK2  (T_CAP / CHUNK)                 // 32
#define GCAP     327680                          // per-group edge capacity

__device__ __forceinline__ const float* feat_row(const float* __restrict__ ue,
                                                 const float* __restrict__ ie, int n) {
    return (n < USER_NUM) ? (ue + (size_t)n * DD)
                          : (ie + (size_t)(n - USER_NUM) * DD);
}

// ---- init: zero cnt2/tmask, seed gcur --------------------------------------

__global__ __launch_bounds__(256) void zero_kernel(int* __restrict__ cnt2,
                                                   int* __restrict__ tmask,
                                                   int* __restrict__ gcur) {
    const int tid    = blockIdx.x * 256 + (int)threadIdx.x;
    const int stride = gridDim.x * 256;
    for (int i = tid; i < T_CAP; i += stride) cnt2[i] = 0;
    for (int i = tid; i < NNODE; i += stride) tmask[i] = 0;
    if (tid < 8) gcur[tid] = tid * GCAP;
}

// ---- Touched-node marking --------------------------------------------------

__global__ __launch_bounds__(256) void mark_kernel(const int* __restrict__ uid,
                                                   const int* __restrict__ iid,
                                                   int* __restrict__ tmask, int B) {
    const int stride = gridDim.x * blockDim.x;
    for (int s = blockIdx.x * blockDim.x + threadIdx.x; s < B; s += stride) {
        tmask[uid[s]] = 1;                       // racing same-value stores: benign
        tmask[USER_NUM + iid[s]] = 1;
    }
}

// ---- Generic 3-phase scan pieces (domain size N as arg) --------------------

__global__ __launch_bounds__(256) void chunksum_kernel(const int* __restrict__ arr,
                                                       int* __restrict__ csum, int N) {
    __shared__ int red[4];
    const int c = blockIdx.x;
    const int t = threadIdx.x;
    int s = 0;
#pragma unroll
    for (int i = 0; i < 4; ++i) {
        const int idx = c * CHUNK + t + 256 * i;
        s += (idx < N) ? arr[idx] : 0;
    }
#pragma unroll
    for (int off = 32; off; off >>= 1) s += __shfl_down(s, off);
    if ((t & 63) == 0) red[t >> 6] = s;
    __syncthreads();
    if (t == 0) csum[c] = red[0] + red[1] + red[2] + red[3];
}

__global__ __launch_bounds__(128) void scan_small_kernel(const int* __restrict__ csum,
                                                         int* __restrict__ coff,
                                                         int NC) {
    __shared__ int s[128];
    const int t = threadIdx.x;
    const int v = (t < NC) ? csum[t] : 0;
    s[t] = v;
    __syncthreads();
    for (int off = 1; off < 128; off <<= 1) {
        const int val = s[t];
        const int add = (t >= off) ? s[t - off] : 0;
        __syncthreads();
        s[t] = val + add;
        __syncthreads();
    }
    if (t < NC) coff[t] = s[t] - v;
}

// Flags fill (NNODE domain): cmapx (slot or -1), nodes, meta[0]=T, meta[1]=Tu,
// gslot[g] = first slot of node-range group g (g=0..8).
__global__ __launch_bounds__(256) void fill_flags_kernel(
    const int* __restrict__ tmask, const int* __restrict__ coff,
    int* __restrict__ cmapx, int* __restrict__ nodes, int* __restrict__ meta,
    int* __restrict__ gslot) {
    __shared__ int sp[256];
    const int c  = blockIdx.x;
    const int t  = threadIdx.x;
    const int g0 = c * CHUNK + t * 4;
    int v[4];
#pragma unroll
    for (int i = 0; i < 4; ++i) v[i] = (g0 + i < NNODE) ? tmask[g0 + i] : 0;
    const int s = ((v[0] + v[1]) + (v[2] + v[3]));
    sp[t] = s;
    __syncthreads();
    for (int off = 1; off < 256; off <<= 1) {
        const int val = sp[t];
        const int add = (t >= off) ? sp[t - off] : 0;
        __syncthreads();
        sp[t] = val + add;
        __syncthreads();
    }
    int run = coff[c] + sp[t] - s;
#pragma unroll
    for (int i = 0; i < 4; ++i) {
        const int g = g0 + i;
        if (g < NNODE) {
            cmapx[g] = v[i] ? run : -1;
            if (v[i]) nodes[run] = g;
            if (g == USER_NUM) meta[1] = run;
            if (g % GROWS == 0) gslot[g / GROWS] = run;
            run += v[i];
        } else if (g == NNODE) {
            meta[0] = run;
            gslot[8] = run;
        }
    }
    if (g0 + 4 == NNODE) { meta[0] = run; gslot[8] = run; }
}

// Counts fill (N-domain, N multiple of 4): base + cursor; base[N]=total.
__global__ __launch_bounds__(256) void fill_kernel(const int* __restrict__ cnt,
                                                   const int* __restrict__ coff,
                                                   int* __restrict__ base,
                                                   int* __restrict__ cursor, int N) {
    __shared__ int sp[256];
    const int c  = blockIdx.x;
    const int t  = threadIdx.x;
    const int g0 = c * CHUNK + t * 4;
    int v[4];
#pragma unroll
    for (int i = 0; i < 4; ++i) v[i] = (g0 + i < N) ? cnt[g0 + i] : 0;
    const int s = ((v[0] + v[1]) + (v[2] + v[3]));
    sp[t] = s;
    __syncthreads();
    for (int off = 1; off < 256; off <<= 1) {
        const int val = sp[t];
        const int add = (t >= off) ? sp[t - off] : 0;
        __syncthreads();
        sp[t] = val + add;
        __syncthreads();
    }
    int run = coff[c] + sp[t] - s;
#pragma unroll
    for (int i = 0; i < 4; ++i) {
        const int g = g0 + i;
        if (g < N) {
            base[g]   = run;
            cursor[g] = run;
            run += v[i];
        }
    }
    if (g0 + 4 == N) base[N] = run;
}

// ---- Pass A: block-aggregated append of TOUCHED edges into 8 segments ------

__global__ __launch_bounds__(256) void append_kernel(
    const int* __restrict__ erow, const int* __restrict__ ecol,
    const float* __restrict__ eval, const int* __restrict__ cmapx,
    int* __restrict__ gcur, int* __restrict__ grow, int2* __restrict__ gpair,
    int E) {
    __shared__ int lcnt[8];
    __shared__ int lbase[8];
    const int t = threadIdx.x;
    if (t < 8) lcnt[t] = 0;
    __syncthreads();
    const int e0 = blockIdx.x * APB + t;
    int sl[EPT], c[EPT], gr[EPT], rk[EPT];
    float v[EPT];
#pragma unroll
    for (int i = 0; i < EPT; ++i) {
        const int e = e0 + 256 * i;
        gr[i] = -1;
        if (e < E) {
            const int r = erow[e];
            const int slot = cmapx[r];
            if (slot >= 0) {
                sl[i] = slot;
                c[i]  = ecol[e];
                v[i]  = eval[e];
                gr[i] = (r * 8) / NNODE;    // const div -> magic mul
                rk[i] = atomicAdd(&lcnt[gr[i]], 1);
            }
        }
    }
    __syncthreads();
    if (t < 8 && lcnt[t] > 0) lbase[t] = atomicAdd(&gcur[t], lcnt[t]);
    __syncthreads();
#pragma unroll
    for (int i = 0; i < EPT; ++i) {
        if (gr[i] >= 0) {
            const int pos = lbase[gr[i]] + rk[i];
            grow[pos]  = sl[i];             // compact slot
            gpair[pos] = make_int2(c[i], __float_as_int(v[i]));
        }
    }
}

// ---- Histogram: per-group LDS histogram over contiguous slot range ----------

__global__ __launch_bounds__(256) void hist3_kernel(const int* __restrict__ grow,
                                                    const int* __restrict__ gcur,
                                                    const int* __restrict__ gslot,
                                                    int* __restrict__ cnt2) {
    __shared__ int hloc[GROWS];
    const int g    = blockIdx.x & 7;
    const int rank = blockIdx.x >> 3;       // 0..NB3-1
    const int slo  = gslot[g];
    const int span = gslot[g + 1] - slo;
    for (int i = threadIdx.x; i < span; i += 256) hloc[i] = 0;
    __syncthreads();
    const int hi = gcur[g];
    for (int i = g * GCAP + rank * 256 + (int)threadIdx.x; i < hi; i += NB3 * 256)
        atomicAdd(&hloc[grow[i] - slo], 1);
    __syncthreads();
    for (int i = threadIdx.x; i < span; i += 256) {
        const int v = hloc[i];
        if (v) atomicAdd(&cnt2[slo + i], v);
    }
}

// ---- Pass B: per-group CSR scatter ------------------------------------------

__global__ __launch_bounds__(256) void scatter2_kernel(
    const int* __restrict__ grow, const int2* __restrict__ gpair,
    const int* __restrict__ gcur, int* __restrict__ cursor2,
    int2* __restrict__ epair) {
    const int g    = blockIdx.x & 7;
    const int rank = blockIdx.x >> 3;       // 0..NS2-1
    const int hi = gcur[g];
    for (int i = g * GCAP + rank * 256 + (int)threadIdx.x; i < hi; i += NS2 * 256) {
        const int slot = grow[i];
        const int pos = atomicAdd(&cursor2[slot], 1);
        epair[pos] = gpair[i];
    }
}

// ---- SpMM over compact touched rows ----------------------------------------

__global__ __launch_bounds__(256) void spmm_kernel(
    const float* __restrict__ ue, const float* __restrict__ ie,
    const int2* __restrict__ epair, const int* __restrict__ base2,
    const int* __restrict__ nodes, const int* __restrict__ meta,
    float* __restrict__ lx, float* __restrict__ lx2) {
    const int T = meta[0];
    const int lane = threadIdx.x & 63;
    int wv = (int)((blockIdx.x * blockDim.x + threadIdx.x) >> 6);
    wv = __builtin_amdgcn_readfirstlane(wv);
    const int nw = (int)((gridDim.x * blockDim.x) >> 6);
    for (int r = wv; r < T; r += nw) {
        const int jb = base2[r];
        const int je = base2[r + 1];
        float acc1 = 0.f, acc2 = 0.f;
        int j = jb;
        for (; j + 8 <= je; j += 8) {
            int2 p[8];
#pragma unroll
            for (int t = 0; t < 8; ++t) p[t] = epair[j + t];
            float f[8];
#pragma unroll
            for (int t = 0; t < 8; ++t) f[t] = feat_row(ue, ie, p[t].x)[lane];
#pragma unroll
            for (int t = 0; t < 8; ++t) {
                const float v = __int_as_float(p[t].y);
                acc1 = fmaf(v, f[t], acc1);
                acc2 = fmaf(v * f[t], f[t], acc2);
            }
        }
        for (; j + 4 <= je; j += 4) {
            int2 p[4];
#pragma unroll
            for (int t = 0; t < 4; ++t) p[t] = epair[j + t];
            float f[4];
#pragma unroll
            for (int t = 0; t < 4; ++t) f[t] = feat_row(ue, ie, p[t].x)[lane];
#pragma unroll
            for (int t = 0; t < 4; ++t) {
                const float v = __int_as_float(p[t].y);
                acc1 = fmaf(v, f[t], acc1);
                acc2 = fmaf(v * f[t], f[t], acc2);
            }
        }
        for (; j < je; ++j) {
            const int2 p = epair[j];
            const float f = feat_row(ue, ie, p.x)[lane];
            const float v = __int_as_float(p.y);
            acc1 = fmaf(v, f, acc1);
            acc2 = fmaf(v * f, f, acc2);
        }
        const int n = nodes[r];
        lx [(size_t)r * DD + lane] = acc1 + feat_row(ue, ie, n)[lane];
        lx2[(size_t)r * DD + lane] = acc2;
    }
}

// ---- Register transform: lane=row, weights via wave-uniform scalar loads ---
// One wave (64 threads) per 64-slot tile. Each lane owns one row fully:
//   phase1: acc[j] = lx[g]@Wg1 + lx2[g]@Wg2; h = lrelu(acc+bg) -> padded LDS
//   phase2: part[g] = f[n]@W1a + h@W1b (+ b1 for users)
// Activations: per-lane contiguous-row gathers (L1-hot 16KB/wave).
// Weights: wave-uniform addresses -> compiler scalarizes to s_load + SGPR fma.
// No DS broadcasts, no barriers (single wave). LDS pad 65 -> 2-way banks (free).

__global__ __launch_bounds__(64) void xform_reg_kernel(
    const float* __restrict__ lx, const float* __restrict__ lx2,
    const float* __restrict__ ue, const float* __restrict__ ie,
    const float* __restrict__ Wg1, const float* __restrict__ Wg2,
    const float* __restrict__ bg1, const float* __restrict__ bg2,
    const float* __restrict__ W1, const float* __restrict__ b1,
    float* __restrict__ part,
    const int* __restrict__ nodes, const int* __restrict__ meta) {
    __shared__ float f_s[64 * 65];
    __shared__ float h_s[64 * 65];
    const int Tu  = meta[1];
    const int T   = meta[0];
    const int nTu = (Tu + 63) >> 6;
    const int tile = blockIdx.x;
    bool isU;
    int rowBase, lim;
    if (tile < nTu) {
        isU = true;  rowBase = tile * 64;              lim = Tu;
    } else {
        isU = false; rowBase = Tu + (tile - nTu) * 64; lim = T;
        if (rowBase >= T) return;
    }
    const int lane = threadIdx.x;             // 64 threads = 1 wave
    const int g    = rowBase + lane;
    const int gc   = min(g, lim - 1);

    // issue f-row gather early (T14 split: latency hides under phase 1)
    int n = nodes[gc];
    if (!isU) n -= USER_NUM;
    const float* fb = isU ? ue : ie;
    const float4* frow = (const float4*)(fb + (size_t)n * DD);
    float4 fr[16];
#pragma unroll
    for (int q = 0; q < 16; ++q) fr[q] = frow[q];

    // phase 1
    float acc[64];
#pragma unroll
    for (int j = 0; j < 64; ++j) acc[j] = 0.f;
    const float* xrow = lx  + (size_t)gc * DD;
    const float* yrow = lx2 + (size_t)gc * DD;
#pragma unroll 2
    for (int k = 0; k < 64; ++k) {
        const float xk = xrow[k];
        const float yk = yrow[k];
        const float* w1k = Wg1 + k * DD;
        const float* w2k = Wg2 + k * DD;
#pragma unroll
        for (int j = 0; j < 64; ++j)
            acc[j] = fmaf(xk, w1k[j], fmaf(yk, w2k[j], acc[j]));
    }

    // h = lrelu(acc + bg1 + bg2) -> h_s; stage f -> f_s; reset acc
#pragma unroll
    for (int j = 0; j < 64; ++j) {
        const float x = acc[j] + bg1[j] + bg2[j];
        h_s[lane * 65 + j] = (x > 0.f) ? x : 0.01f * x;
        acc[j] = 0.f;
    }
#pragma unroll
    for (int q = 0; q < 16; ++q) {
        const int b = lane * 65 + 4 * q;
        f_s[b]     = fr[q].x;
        f_s[b + 1] = fr[q].y;
        f_s[b + 2] = fr[q].z;
        f_s[b + 3] = fr[q].w;
    }
    // single wave: in-order DS, no barrier needed

    // phase 2
    const float* W1a = W1 + (isU ? 0 : 2 * DD * DD);
    const float* W1b = W1a + DD * DD;
#pragma unroll 2
    for (int k = 0; k < 64; ++k) {
        const float fk = f_s[lane * 65 + k];
        const float hk = h_s[lane * 65 + k];
        const float* wak = W1a + k * DD;
        const float* wbk = W1b + k * DD;
#pragma unroll
        for (int j = 0; j < 64; ++j)
            acc[j] = fmaf(fk, wak[j], fmaf(hk, wbk[j], acc[j]));
    }

    if (g < lim) {
        float4* orow = (float4*)(part + (size_t)g * DD);
#pragma unroll
        for (int q = 0; q < 16; ++q) {
            float4 v;
            v.x = acc[4 * q];     v.y = acc[4 * q + 1];
            v.z = acc[4 * q + 2]; v.w = acc[4 * q + 3];
            if (isU) {
                v.x += b1[4 * q];     v.y += b1[4 * q + 1];
                v.z += b1[4 * q + 2]; v.w += b1[4 * q + 3];
            }
            orow[q] = v;
        }
    }
}

// ---- Per-sample MLP: o1 = relu(part_u + part_i); layers 2,3 ----------------

__global__ __launch_bounds__(256) void mlp_kernel(
    const float* __restrict__ part, const int* __restrict__ cmapx,
    const float* __restrict__ W2, const float* __restrict__ b2,
    const float* __restrict__ W3, const float* __restrict__ b3,
    const int* __restrict__ uid, const int* __restrict__ iid,
    float* __restrict__ out, int B) {
    __shared__ float sW2[DD * 32];
    __shared__ float sW3[32];
    for (int i = threadIdx.x; i < DD * 32; i += 256) sW2[i] = W2[i];
    if (threadIdx.x < 32) sW3[threadIdx.x] = W3[threadIdx.x];
    __syncthreads();
    const int lane = threadIdx.x & 63;
    const int wave = (int)((blockIdx.x * blockDim.x + threadIdx.x) >> 6);
    const int nw   = (int)((gridDim.x * blockDim.x) >> 6);
    const float bias2 = b2[lane & 31];
    const float w3v   = sW3[lane & 31];
    const float bias3 = b3[0];
    for (int s = wave; s < B; s += nw) {
        const int su = cmapx[uid[s]];
        const int si = cmapx[USER_NUM + iid[s]];
        const float pu = part[(size_t)su * DD + lane];
        const float pi = part[(size_t)si * DD + lane];
        const float x  = pu + pi;
        const float o1 = (x > 0.f) ? x : 0.f;
        float acc_a = bias2, acc_b = 0.f;
#pragma unroll
        for (int k = 0; k < DD; k += 2) {
            acc_a = fmaf(__shfl(o1, k),     sW2[k * 32 + (lane & 31)],       acc_a);
            acc_b = fmaf(__shfl(o1, k + 1), sW2[(k + 1) * 32 + (lane & 31)], acc_b);
        }
        const float a2 = acc_a + acc_b;
        const float o2 = (a2 > 0.f) ? a2 : 0.f;
        float p = o2 * w3v;
        p += __shfl_xor(p, 1);
        p += __shfl_xor(p, 2);
        p += __shfl_xor(p, 4);
        p += __shfl_xor(p, 8);
        p += __shfl_xor(p, 16);
        if (lane == 0) out[s] = p + bias3;
    }
}

extern "C" void kernel_launch(void* const* d_in, const int* in_sizes, int n_in,
                              void* d_out, int out_size, void* d_ws, size_t ws_size,
                              hipStream_t stream) {
    const float* ue   = (const float*)d_in[0];
    const float* ie   = (const float*)d_in[1];
    const int*   erow = (const int*)d_in[2];
    const int*   ecol = (const int*)d_in[3];
    const float* evalp= (const float*)d_in[4];
    const float* Wg1  = (const float*)d_in[5];
    const float* bg1  = (const float*)d_in[6];
    const float* Wg2  = (const float*)d_in[7];
    const float* bg2  = (const float*)d_in[8];
    const float* W1   = (const float*)d_in[9];
    const float* b1   = (const float*)d_in[10];
    const float* W2   = (const float*)d_in[11];
    const float* b2   = (const float*)d_in[12];
    const float* W3   = (const float*)d_in[13];
    const float* b3   = (const float*)d_in[14];
    const int*   uid  = (const int*)d_in[15];
    const int*   iid  = (const int*)d_in[16];
    float* out = (float*)d_out;

    const int E = in_sizes[2];
    const int B = in_sizes[15];

    const int TU_MAX = (B < USER_NUM) ? B : USER_NUM;   // touched users <= B
    const int TI_MAX = (B < ITEM_NUM) ? B : ITEM_NUM;   // touched items <= B
    const int nTiles = (TU_MAX + 63) / 64 + (TI_MAX + 63) / 64;   // 512

    // workspace layout (~49.5 MB peak):
    //  [A: 32MB  lx|lx2|part (8MB each, compact T_CAP rows) + 8MB spare]
    //    - during CSR build, grow(10.5MB)+gpair(21MB) overlay region A
    //      (both dead before spmm writes lx/lx2)
    //  [B: epair 16MB]
    //  [C: misc ints ~1.2MB]
    char* ws = (char*)d_ws;
    const size_t ndc = (size_t)T_CAP * DD;              // 8MB per array
    float* lx    = (float*)ws;
    float* lx2   = lx + ndc;
    float* part  = lx2 + ndc;
    int*   grow  = (int*)ws;                            // 8*GCAP ints (10.5MB)
    int2*  gpair = (int2*)(ws + 11u * 1024 * 1024);     // 8*GCAP int2 (21MB)
    char*  tail  = ws + 32u * 1024 * 1024;
    int2*  epair = (int2*)tail;                         // E int2 = 16MB
    int*   mi    = (int*)(tail + (size_t)E * sizeof(int2));
    int*   cnt2    = mi;                                // T_CAP
    int*   cursor2 = cnt2 + T_CAP;                      // T_CAP
    int*   base2   = cursor2 + T_CAP;                   // T_CAP+1
    int*   tmask   = base2 + T_CAP + 1;                 // NNODE
    int*   cmapx   = tmask + NNODE;                     // NNODE
    int*   nodes   = cmapx + NNODE;                     // T_CAP
    int*   csum    = nodes + T_CAP;                     // 128
    int*   coff    = csum + 128;                        // 128
    int*   gcur    = coff + 128;                        // 8
    int*   meta    = gcur + 8;                          // [0]=T, [1]=Tu
    int*   gslot   = meta + 8;                          // 9 ints

    zero_kernel<<<512, 256, 0, stream>>>(cnt2, tmask, gcur);
    mark_kernel<<<(B + 255) / 256, 256, 0, stream>>>(uid, iid, tmask, B);
    chunksum_kernel<<<NCHUNK, 256, 0, stream>>>(tmask, csum, NNODE);
    scan_small_kernel<<<1, 128, 0, stream>>>(csum, coff, NCHUNK);
    fill_flags_kernel<<<NCHUNK, 256, 0, stream>>>(tmask, coff, cmapx, nodes,
                                                  meta, gslot);
    append_kernel<<<(E + APB - 1) / APB, 256, 0, stream>>>(
        erow, ecol, evalp, cmapx, gcur, grow, gpair, E);
    hist3_kernel<<<8 * NB3, 256, 0, stream>>>(grow, gcur, gslot, cnt2);
    chunksum_kernel<<<NCHUNK2, 256, 0, stream>>>(cnt2, csum, T_CAP);
    scan_small_kernel<<<1, 128, 0, stream>>>(csum, coff, NCHUNK2);
    fill_kernel<<<NCHUNK2, 256, 0, stream>>>(cnt2, coff, base2, cursor2, T_CAP);
    scatter2_kernel<<<8 * NS2, 256, 0, stream>>>(grow, gpair, gcur, cursor2, epair);
    spmm_kernel<<<4096, 256, 0, stream>>>(ue, ie, epair, base2, nodes, meta,
                                          lx, lx2);

    // register transform: one wave per 64-slot tile, no DS broadcasts
    xform_reg_kernel<<<nTiles, 64, 0, stream>>>(
        lx, lx2, ue, ie, Wg1, Wg2, bg1, bg2, W1, b1, part, nodes, meta);

    mlp_kernel<<<1024, 256, 0, stream>>>(part, cmapx, W2, b2, W3, b3,
                                         uid, iid, out, B);
}

// Round 18
// 228.876 us; speedup vs baseline: 1.1382x; 1.1382x over previous
//
#include <hip/hip_runtime.h>
#include <hip/hip_bf16.h>

#define USER_NUM 50000
#define ITEM_NUM 20000
#define NNODE    70000
#define DD       64
#define CHUNK    1024
#define NCHUNK   ((NNODE + CHUNK - 1) / CHUNK)   // 69
#define GROWS    (NNODE / 8)                     // 8750 rows per coarse group
#define APB      2048                            // append: edges per block
#define EPT      8                               // append: edges per thread
#define NS2      128                             // scatter2 stripes per group
#define NB3      16                              // hist3 blocks per group
#define T_CAP    32768                           // max touched slots (B=16384)
#define NCHUNK2  (T_CAP / CHUNK)                 // 32
#define GCAP     327680                          // per-group edge capacity
#define XR       4                               // xform rows per wave
#define TILE_R   16                              // rows per block (4 waves * XR)

__device__ __forceinline__ const float* feat_row(const float* __restrict__ ue,
                                                 const float* __restrict__ ie, int n) {
    return (n < USER_NUM) ? (ue + (size_t)n * DD)
                          : (ie + (size_t)(n - USER_NUM) * DD);
}

__device__ __forceinline__ float rdlane(float v, int k) {
    return __int_as_float(__builtin_amdgcn_readlane(__float_as_int(v), k));
}

// ---- init: zero cnt2/tmask, seed gcur --------------------------------------

__global__ __launch_bounds__(256) void zero_kernel(int* __restrict__ cnt2,
                                                   int* __restrict__ tmask,
                                                   int* __restrict__ gcur) {
    const int tid    = blockIdx.x * 256 + (int)threadIdx.x;
    const int stride = gridDim.x * 256;
    for (int i = tid; i < T_CAP; i += stride) cnt2[i] = 0;
    for (int i = tid; i < NNODE; i += stride) tmask[i] = 0;
    if (tid < 8) gcur[tid] = tid * GCAP;
}

// ---- Touched-node marking --------------------------------------------------

__global__ __launch_bounds__(256) void mark_kernel(const int* __restrict__ uid,
                                                   const int* __restrict__ iid,
                                                   int* __restrict__ tmask, int B) {
    const int stride = gridDim.x * blockDim.x;
    for (int s = blockIdx.x * blockDim.x + threadIdx.x; s < B; s += stride) {
        tmask[uid[s]] = 1;                       // racing same-value stores: benign
        tmask[USER_NUM + iid[s]] = 1;
    }
}

// ---- Generic 3-phase scan pieces (domain size N as arg) --------------------

__global__ __launch_bounds__(256) void chunksum_kernel(const int* __restrict__ arr,
                                                       int* __restrict__ csum, int N) {
    __shared__ int red[4];
    const int c = blockIdx.x;
    const int t = threadIdx.x;
    int s = 0;
#pragma unroll
    for (int i = 0; i < 4; ++i) {
        const int idx = c * CHUNK + t + 256 * i;
        s += (idx < N) ? arr[idx] : 0;
    }
#pragma unroll
    for (int off = 32; off; off >>= 1) s += __shfl_down(s, off);
    if ((t & 63) == 0) red[t >> 6] = s;
    __syncthreads();
    if (t == 0) csum[c] = red[0] + red[1] + red[2] + red[3];
}

__global__ __launch_bounds__(128) void scan_small_kernel(const int* __restrict__ csum,
                                                         int* __restrict__ coff,
                                                         int NC) {
    __shared__ int s[128];
    const int t = threadIdx.x;
    const int v = (t < NC) ? csum[t] : 0;
    s[t] = v;
    __syncthreads();
    for (int off = 1; off < 128; off <<= 1) {
        const int val = s[t];
        const int add = (t >= off) ? s[t - off] : 0;
        __syncthreads();
        s[t] = val + add;
        __syncthreads();
    }
    if (t < NC) coff[t] = s[t] - v;
}

// Flags fill (NNODE domain): cmapx (slot or -1), nodes, meta[0]=T, meta[1]=Tu,
// gslot[g] = first slot of node-range group g (g=0..8).
__global__ __launch_bounds__(256) void fill_flags_kernel(
    const int* __restrict__ tmask, const int* __restrict__ coff,
    int* __restrict__ cmapx, int* __restrict__ nodes, int* __restrict__ meta,
    int* __restrict__ gslot) {
    __shared__ int sp[256];
    const int c  = blockIdx.x;
    const int t  = threadIdx.x;
    const int g0 = c * CHUNK + t * 4;
    int v[4];
#pragma unroll
    for (int i = 0; i < 4; ++i) v[i] = (g0 + i < NNODE) ? tmask[g0 + i] : 0;
    const int s = ((v[0] + v[1]) + (v[2] + v[3]));
    sp[t] = s;
    __syncthreads();
    for (int off = 1; off < 256; off <<= 1) {
        const int val = sp[t];
        const int add = (t >= off) ? sp[t - off] : 0;
        __syncthreads();
        sp[t] = val + add;
        __syncthreads();
    }
    int run = coff[c] + sp[t] - s;
#pragma unroll
    for (int i = 0; i < 4; ++i) {
        const int g = g0 + i;
        if (g < NNODE) {
            cmapx[g] = v[i] ? run : -1;
            if (v[i]) nodes[run] = g;
            if (g == USER_NUM) meta[1] = run;
            if (g % GROWS == 0) gslot[g / GROWS] = run;
            run += v[i];
        } else if (g == NNODE) {
            meta[0] = run;
            gslot[8] = run;
        }
    }
    if (g0 + 4 == NNODE) { meta[0] = run; gslot[8] = run; }
}

// Counts fill (N-domain, N multiple of 4): base + cursor; base[N]=total.
__global__ __launch_bounds__(256) void fill_kernel(const int* __restrict__ cnt,
                                                   const int* __restrict__ coff,
                                                   int* __restrict__ base,
                                                   int* __restrict__ cursor, int N) {
    __shared__ int sp[256];
    const int c  = blockIdx.x;
    const int t  = threadIdx.x;
    const int g0 = c * CHUNK + t * 4;
    int v[4];
#pragma unroll
    for (int i = 0; i < 4; ++i) v[i] = (g0 + i < N) ? cnt[g0 + i] : 0;
    const int s = ((v[0] + v[1]) + (v[2] + v[3]));
    sp[t] = s;
    __syncthreads();
    for (int off = 1; off < 256; off <<= 1) {
        const int val = sp[t];
        const int add = (t >= off) ? sp[t - off] : 0;
        __syncthreads();
        sp[t] = val + add;
        __syncthreads();
    }
    int run = coff[c] + sp[t] - s;
#pragma unroll
    for (int i = 0; i < 4; ++i) {
        const int g = g0 + i;
        if (g < N) {
            base[g]   = run;
            cursor[g] = run;
            run += v[i];
        }
    }
    if (g0 + 4 == N) base[N] = run;
}

// ---- Pass A: block-aggregated append of TOUCHED edges into 8 segments ------

__global__ __launch_bounds__(256) void append_kernel(
    const int* __restrict__ erow, const int* __restrict__ ecol,
    const float* __restrict__ eval, const int* __restrict__ cmapx,
    int* __restrict__ gcur, int* __restrict__ grow, int2* __restrict__ gpair,
    int E) {
    __shared__ int lcnt[8];
    __shared__ int lbase[8];
    const int t = threadIdx.x;
    if (t < 8) lcnt[t] = 0;
    __syncthreads();
    const int e0 = blockIdx.x * APB + t;
    int sl[EPT], c[EPT], gr[EPT], rk[EPT];
    float v[EPT];
#pragma unroll
    for (int i = 0; i < EPT; ++i) {
        const int e = e0 + 256 * i;
        gr[i] = -1;
        if (e < E) {
            const int r = erow[e];
            const int slot = cmapx[r];
            if (slot >= 0) {
                sl[i] = slot;
                c[i]  = ecol[e];
                v[i]  = eval[e];
                gr[i] = (r * 8) / NNODE;    // const div -> magic mul
                rk[i] = atomicAdd(&lcnt[gr[i]], 1);
            }
        }
    }
    __syncthreads();
    if (t < 8 && lcnt[t] > 0) lbase[t] = atomicAdd(&gcur[t], lcnt[t]);
    __syncthreads();
#pragma unroll
    for (int i = 0; i < EPT; ++i) {
        if (gr[i] >= 0) {
            const int pos = lbase[gr[i]] + rk[i];
            grow[pos]  = sl[i];             // compact slot
            gpair[pos] = make_int2(c[i], __float_as_int(v[i]));
        }
    }
}

// ---- Histogram: per-group LDS histogram over contiguous slot range ----------

__global__ __launch_bounds__(256) void hist3_kernel(const int* __restrict__ grow,
                                                    const int* __restrict__ gcur,
                                                    const int* __restrict__ gslot,
                                                    int* __restrict__ cnt2) {
    __shared__ int hloc[GROWS];
    const int g    = blockIdx.x & 7;
    const int rank = blockIdx.x >> 3;       // 0..NB3-1
    const int slo  = gslot[g];
    const int span = gslot[g + 1] - slo;
    for (int i = threadIdx.x; i < span; i += 256) hloc[i] = 0;
    __syncthreads();
    const int hi = gcur[g];
    for (int i = g * GCAP + rank * 256 + (int)threadIdx.x; i < hi; i += NB3 * 256)
        atomicAdd(&hloc[grow[i] - slo], 1);
    __syncthreads();
    for (int i = threadIdx.x; i < span; i += 256) {
        const int v = hloc[i];
        if (v) atomicAdd(&cnt2[slo + i], v);
    }
}

// ---- Pass B: per-group CSR scatter ------------------------------------------

__global__ __launch_bounds__(256) void scatter2_kernel(
    const int* __restrict__ grow, const int2* __restrict__ gpair,
    const int* __restrict__ gcur, int* __restrict__ cursor2,
    int2* __restrict__ epair) {
    const int g    = blockIdx.x & 7;
    const int rank = blockIdx.x >> 3;       // 0..NS2-1
    const int hi = gcur[g];
    for (int i = g * GCAP + rank * 256 + (int)threadIdx.x; i < hi; i += NS2 * 256) {
        const int slot = grow[i];
        const int pos = atomicAdd(&cursor2[slot], 1);
        epair[pos] = gpair[i];
    }
}

// ---- SpMM over compact touched rows ----------------------------------------

__global__ __launch_bounds__(256) void spmm_kernel(
    const float* __restrict__ ue, const float* __restrict__ ie,
    const int2* __restrict__ epair, const int* __restrict__ base2,
    const int* __restrict__ nodes, const int* __restrict__ meta,
    float* __restrict__ lx, float* __restrict__ lx2) {
    const int T = meta[0];
    const int lane = threadIdx.x & 63;
    int wv = (int)((blockIdx.x * blockDim.x + threadIdx.x) >> 6);
    wv = __builtin_amdgcn_readfirstlane(wv);
    const int nw = (int)((gridDim.x * blockDim.x) >> 6);
    for (int r = wv; r < T; r += nw) {
        const int jb = base2[r];
        const int je = base2[r + 1];
        float acc1 = 0.f, acc2 = 0.f;
        int j = jb;
        for (; j + 8 <= je; j += 8) {
            int2 p[8];
#pragma unroll
            for (int t = 0; t < 8; ++t) p[t] = epair[j + t];
            float f[8];
#pragma unroll
            for (int t = 0; t < 8; ++t) f[t] = feat_row(ue, ie, p[t].x)[lane];
#pragma unroll
            for (int t = 0; t < 8; ++t) {
                const float v = __int_as_float(p[t].y);
                acc1 = fmaf(v, f[t], acc1);
                acc2 = fmaf(v * f[t], f[t], acc2);
            }
        }
        for (; j + 4 <= je; j += 4) {
            int2 p[4];
#pragma unroll
            for (int t = 0; t < 4; ++t) p[t] = epair[j + t];
            float f[4];
#pragma unroll
            for (int t = 0; t < 4; ++t) f[t] = feat_row(ue, ie, p[t].x)[lane];
#pragma unroll
            for (int t = 0; t < 4; ++t) {
                const float v = __int_as_float(p[t].y);
                acc1 = fmaf(v, f[t], acc1);
                acc2 = fmaf(v * f[t], f[t], acc2);
            }
        }
        for (; j < je; ++j) {
            const int2 p = epair[j];
            const float f = feat_row(ue, ie, p.x)[lane];
            const float v = __int_as_float(p.y);
            acc1 = fmaf(v, f, acc1);
            acc2 = fmaf(v * f, f, acc2);
        }
        const int n = nodes[r];
        lx [(size_t)r * DD + lane] = acc1 + feat_row(ue, ie, r < 0 ? 0 : n)[lane];
        lx2[(size_t)r * DD + lane] = acc2;
    }
}

// ---- Readlane transform: lane = output col, activations via v_readlane -----
// Each wave owns XR=4 rows. Per row: load lx/lx2/f coalesced (lane=k),
// broadcast each k via v_readlane (VALU pipe — zero DS ops, zero barriers),
// weights statically indexed in 128 VGPRs (k fully unrolled).
//   phase1: h[i] = lrelu(lx@Wg1 + lx2@Wg2 + bg)     (1 VGPR per row)
//   phase2: part  = f@W1a + h@W1b (+ b1 for users)

__global__ __launch_bounds__(256) void xform_rl_kernel(
    const float* __restrict__ lx, const float* __restrict__ lx2,
    const float* __restrict__ ue, const float* __restrict__ ie,
    const float* __restrict__ Wg1, const float* __restrict__ Wg2,
    const float* __restrict__ bg1, const float* __restrict__ bg2,
    const float* __restrict__ W1, const float* __restrict__ b1,
    float* __restrict__ part,
    const int* __restrict__ nodes, const int* __restrict__ meta, int nTilesU) {
    const int Tu = meta[1];
    const int T  = meta[0];
    const bool isU   = (int)blockIdx.x < nTilesU;
    const int tileIx = isU ? blockIdx.x : (blockIdx.x - nTilesU);
    const int start  = isU ? 0  : Tu;
    const int lim    = isU ? Tu : T;
    const int w      = threadIdx.x >> 6;
    const int lane   = threadIdx.x & 63;
    const int r0     = start + tileIx * TILE_R + w * XR;
    if (r0 >= lim) return;

    const float bgs = bg1[lane] + bg2[lane];

    int g[XR], gc[XR];
#pragma unroll
    for (int i = 0; i < XR; ++i) {
        g[i]  = r0 + i;
        gc[i] = min(g[i], lim - 1);
    }

    float vx[XR], vy[XR];
#pragma unroll
    for (int i = 0; i < XR; ++i) {
        vx[i] = lx [(size_t)gc[i] * DD + lane];
        vy[i] = lx2[(size_t)gc[i] * DD + lane];
    }

    // phase-1 weights in VGPRs (static index; k fully unrolled below)
    float wa[DD], wb[DD];
#pragma unroll
    for (int k = 0; k < DD; ++k) {
        wa[k] = Wg1[k * DD + lane];
        wb[k] = Wg2[k * DD + lane];
    }

    float acc[XR];
#pragma unroll
    for (int i = 0; i < XR; ++i) acc[i] = bgs;
#pragma unroll
    for (int k = 0; k < DD; ++k) {
#pragma unroll
        for (int i = 0; i < XR; ++i) {
            const float xk = rdlane(vx[i], k);
            const float yk = rdlane(vy[i], k);
            acc[i] = fmaf(xk, wa[k], fmaf(yk, wb[k], acc[i]));
        }
    }
    float h[XR];
#pragma unroll
    for (int i = 0; i < XR; ++i)
        h[i] = (acc[i] > 0.f) ? acc[i] : 0.01f * acc[i];

    // f rows (coalesced; row base is wave-uniform -> scalar-based addressing)
    float vf[XR];
    const float* fb = isU ? ue : ie;
#pragma unroll
    for (int i = 0; i < XR; ++i) {
        int n = nodes[gc[i]];
        if (!isU) n -= USER_NUM;
        vf[i] = fb[(size_t)n * DD + lane];
    }

    // phase-2 weights (reuse wa/wb registers)
    const float* W1a = W1 + (isU ? 0 : 2 * DD * DD);
    const float* W1b = W1a + DD * DD;
#pragma unroll
    for (int k = 0; k < DD; ++k) {
        wa[k] = W1a[k * DD + lane];
        wb[k] = W1b[k * DD + lane];
    }

    const float b1v = isU ? b1[lane] : 0.f;
#pragma unroll
    for (int i = 0; i < XR; ++i) acc[i] = b1v;
#pragma unroll
    for (int k = 0; k < DD; ++k) {
#pragma unroll
        for (int i = 0; i < XR; ++i) {
            const float fk = rdlane(vf[i], k);
            const float hk = rdlane(h[i], k);
            acc[i] = fmaf(fk, wa[k], fmaf(hk, wb[k], acc[i]));
        }
    }

#pragma unroll
    for (int i = 0; i < XR; ++i)
        if (g[i] < lim) part[(size_t)g[i] * DD + lane] = acc[i];
}

// ---- Per-sample MLP: o1 = relu(part_u + part_i); layers 2,3 ----------------

__global__ __launch_bounds__(256) void mlp_kernel(
    const float* __restrict__ part, const int* __restrict__ cmapx,
    const float* __restrict__ W2, const float* __restrict__ b2,
    const float* __restrict__ W3, const float* __restrict__ b3,
    const int* __restrict__ uid, const int* __restrict__ iid,
    float* __restrict__ out, int B) {
    __shared__ float sW2[DD * 32];
    __shared__ float sW3[32];
    for (int i = threadIdx.x; i < DD * 32; i += 256) sW2[i] = W2[i];
    if (threadIdx.x < 32) sW3[threadIdx.x] = W3[threadIdx.x];
    __syncthreads();
    const int lane = threadIdx.x & 63;
    const int wave = (int)((blockIdx.x * blockDim.x + threadIdx.x) >> 6);
    const int nw   = (int)((gridDim.x * blockDim.x) >> 6);
    const float bias2 = b2[lane & 31];
    const float w3v   = sW3[lane & 31];
    const float bias3 = b3[0];
    for (int s = wave; s < B; s += nw) {
        const int su = cmapx[uid[s]];
        const int si = cmapx[USER_NUM + iid[s]];
        const float pu = part[(size_t)su * DD + lane];
        const float pi = part[(size_t)si * DD + lane];
        const float x  = pu + pi;
        const float o1 = (x > 0.f) ? x : 0.f;
        float acc_a = bias2, acc_b = 0.f;
#pragma unroll
        for (int k = 0; k < DD; k += 2) {
            acc_a = fmaf(__shfl(o1, k),     sW2[k * 32 + (lane & 31)],       acc_a);
            acc_b = fmaf(__shfl(o1, k + 1), sW2[(k + 1) * 32 + (lane & 31)], acc_b);
        }
        const float a2 = acc_a + acc_b;
        const float o2 = (a2 > 0.f) ? a2 : 0.f;
        float p = o2 * w3v;
        p += __shfl_xor(p, 1);
        p += __shfl_xor(p, 2);
        p += __shfl_xor(p, 4);
        p += __shfl_xor(p, 8);
        p += __shfl_xor(p, 16);
        if (lane == 0) out[s] = p + bias3;
    }
}

extern "C" void kernel_launch(void* const* d_in, const int* in_sizes, int n_in,
                              void* d_out, int out_size, void* d_ws, size_t ws_size,
                              hipStream_t stream) {
    const float* ue   = (const float*)d_in[0];
    const float* ie   = (const float*)d_in[1];
    const int*   erow = (const int*)d_in[2];
    const int*   ecol = (const int*)d_in[3];
    const float* evalp= (const float*)d_in[4];
    const float* Wg1  = (const float*)d_in[5];
    const float* bg1  = (const float*)d_in[6];
    const float* Wg2  = (const float*)d_in[7];
    const float* bg2  = (const float*)d_in[8];
    const float* W1   = (const float*)d_in[9];
    const float* b1   = (const float*)d_in[10];
    const float* W2   = (const float*)d_in[11];
    const float* b2   = (const float*)d_in[12];
    const float* W3   = (const float*)d_in[13];
    const float* b3   = (const float*)d_in[14];
    const int*   uid  = (const int*)d_in[15];
    const int*   iid  = (const int*)d_in[16];
    float* out = (float*)d_out;

    const int E = in_sizes[2];
    const int B = in_sizes[15];

    const int TU_MAX = (B < USER_NUM) ? B : USER_NUM;   // touched users <= B
    const int TI_MAX = (B < ITEM_NUM) ? B : ITEM_NUM;   // touched items <= B
    const int nTilesU = (TU_MAX + TILE_R - 1) / TILE_R;
    const int nTilesI = (TI_MAX + TILE_R - 1) / TILE_R;

    // workspace layout (~49.5 MB peak):
    //  [A: 32MB  lx|lx2|part (8MB each, compact T_CAP rows) + 8MB spare]
    //    - during CSR build, grow(10.5MB)+gpair(21MB) overlay region A
    //      (both dead before spmm writes lx/lx2)
    //  [B: epair 16MB]
    //  [C: misc ints ~1.2MB]
    char* ws = (char*)d_ws;
    const size_t ndc = (size_t)T_CAP * DD;              // 8MB per array
    float* lx    = (float*)ws;
    float* lx2   = lx + ndc;
    float* part  = lx2 + ndc;
    int*   grow  = (int*)ws;                            // 8*GCAP ints (10.5MB)
    int2*  gpair = (int2*)(ws + 11u * 1024 * 1024);     // 8*GCAP int2 (21MB)
    char*  tail  = ws + 32u * 1024 * 1024;
    int2*  epair = (int2*)tail;                         // E int2 = 16MB
    int*   mi    = (int*)(tail + (size_t)E * sizeof(int2));
    int*   cnt2    = mi;                                // T_CAP
    int*   cursor2 = cnt2 + T_CAP;                      // T_CAP
    int*   base2   = cursor2 + T_CAP;                   // T_CAP+1
    int*   tmask   = base2 + T_CAP + 1;                 // NNODE
    int*   cmapx   = tmask + NNODE;                     // NNODE
    int*   nodes   = cmapx + NNODE;                     // T_CAP
    int*   csum    = nodes + T_CAP;                     // 128
    int*   coff    = csum + 128;                        // 128
    int*   gcur    = coff + 128;                        // 8
    int*   meta    = gcur + 8;                          // [0]=T, [1]=Tu
    int*   gslot   = meta + 8;                          // 9 ints

    zero_kernel<<<512, 256, 0, stream>>>(cnt2, tmask, gcur);
    mark_kernel<<<(B + 255) / 256, 256, 0, stream>>>(uid, iid, tmask, B);
    chunksum_kernel<<<NCHUNK, 256, 0, stream>>>(tmask, csum, NNODE);
    scan_small_kernel<<<1, 128, 0, stream>>>(csum, coff, NCHUNK);
    fill_flags_kernel<<<NCHUNK, 256, 0, stream>>>(tmask, coff, cmapx, nodes,
                                                  meta, gslot);
    append_kernel<<<(E + APB - 1) / APB, 256, 0, stream>>>(
        erow, ecol, evalp, cmapx, gcur, grow, gpair, E);
    hist3_kernel<<<8 * NB3, 256, 0, stream>>>(grow, gcur, gslot, cnt2);
    chunksum_kernel<<<NCHUNK2, 256, 0, stream>>>(cnt2, csum, T_CAP);
    scan_small_kernel<<<1, 128, 0, stream>>>(csum, coff, NCHUNK2);
    fill_kernel<<<NCHUNK2, 256, 0, stream>>>(cnt2, coff, base2, cursor2, T_CAP);
    scatter2_kernel<<<8 * NS2, 256, 0, stream>>>(grow, gpair, gcur, cursor2, epair);
    spmm_kernel<<<4096, 256, 0, stream>>>(ue, ie, epair, base2, nodes, meta,
                                          lx, lx2);

    // readlane transform: one launch covers user + item tiles
    xform_rl_kernel<<<nTilesU + nTilesI, 256, 0, stream>>>(
        lx, lx2, ue, ie, Wg1, Wg2, bg1, bg2, W1, b1, part, nodes, meta, nTilesU);

    mlp_kernel<<<1024, 256, 0, stream>>>(part, cmapx, W2, b2, W3, b3,
                                         uid, iid, out, B);
}

// Round 19
// 204.105 us; speedup vs baseline: 1.2763x; 1.1214x over previous
//
#include <hip/hip_runtime.h>
#include <hip/hip_bf16.h>

#define USER_NUM 50000
#define ITEM_NUM 20000
#define NNODE    70000
#define DD       64
#define CHUNK    1024
#define NCHUNK   ((NNODE + CHUNK - 1) / CHUNK)   // 69
#define GROWS    (NNODE / 8)                     // 8750 rows per coarse group
#define APB      2048                            // append: edges per block
#define EPT      8                               // append: edges per thread
#define NS2      128                             // scatter2 stripes per group
#define NB3      16                              // hist3 blocks per group
#define T_CAP    32768                           // max touched slots (B=16384)
#define NCHUNK2  (T_CAP / CHUNK)                 // 32
#define GCAP     327680                          // per-group edge capacity
#define RT       16                              // xform tile rows (12KB LDS)

__device__ __forceinline__ const float* feat_row(const float* __restrict__ ue,
                                                 const float* __restrict__ ie, int n) {
    return (n < USER_NUM) ? (ue + (size_t)n * DD)
                          : (ie + (size_t)(n - USER_NUM) * DD);
}

// ---- init: zero cnt2/tmask, seed gcur --------------------------------------

__global__ __launch_bounds__(256) void zero_kernel(int* __restrict__ cnt2,
                                                   int* __restrict__ tmask,
                                                   int* __restrict__ gcur) {
    const int tid    = blockIdx.x * 256 + (int)threadIdx.x;
    const int stride = gridDim.x * 256;
    for (int i = tid; i < T_CAP; i += stride) cnt2[i] = 0;
    for (int i = tid; i < NNODE; i += stride) tmask[i] = 0;
    if (tid < 8) gcur[tid] = tid * GCAP;
}

// ---- Touched-node marking --------------------------------------------------

__global__ __launch_bounds__(256) void mark_kernel(const int* __restrict__ uid,
                                                   const int* __restrict__ iid,
                                                   int* __restrict__ tmask, int B) {
    const int stride = gridDim.x * blockDim.x;
    for (int s = blockIdx.x * blockDim.x + threadIdx.x; s < B; s += stride) {
        tmask[uid[s]] = 1;                       // racing same-value stores: benign
        tmask[USER_NUM + iid[s]] = 1;
    }
}

// ---- Generic 3-phase scan pieces (domain size N as arg) --------------------

__global__ __launch_bounds__(256) void chunksum_kernel(const int* __restrict__ arr,
                                                       int* __restrict__ csum, int N) {
    __shared__ int red[4];
    const int c = blockIdx.x;
    const int t = threadIdx.x;
    int s = 0;
#pragma unroll
    for (int i = 0; i < 4; ++i) {
        const int idx = c * CHUNK + t + 256 * i;
        s += (idx < N) ? arr[idx] : 0;
    }
#pragma unroll
    for (int off = 32; off; off >>= 1) s += __shfl_down(s, off);
    if ((t & 63) == 0) red[t >> 6] = s;
    __syncthreads();
    if (t == 0) csum[c] = red[0] + red[1] + red[2] + red[3];
}

__global__ __launch_bounds__(128) void scan_small_kernel(const int* __restrict__ csum,
                                                         int* __restrict__ coff,
                                                         int NC) {
    __shared__ int s[128];
    const int t = threadIdx.x;
    const int v = (t < NC) ? csum[t] : 0;
    s[t] = v;
    __syncthreads();
    for (int off = 1; off < 128; off <<= 1) {
        const int val = s[t];
        const int add = (t >= off) ? s[t - off] : 0;
        __syncthreads();
        s[t] = val + add;
        __syncthreads();
    }
    if (t < NC) coff[t] = s[t] - v;
}

// Flags fill (NNODE domain): cmapx (slot or -1), nodes, meta[0]=T, meta[1]=Tu,
// gslot[g] = first slot of node-range group g (g=0..8).
__global__ __launch_bounds__(256) void fill_flags_kernel(
    const int* __restrict__ tmask, const int* __restrict__ coff,
    int* __restrict__ cmapx, int* __restrict__ nodes, int* __restrict__ meta,
    int* __restrict__ gslot) {
    __shared__ int sp[256];
    const int c  = blockIdx.x;
    const int t  = threadIdx.x;
    const int g0 = c * CHUNK + t * 4;
    int v[4];
#pragma unroll
    for (int i = 0; i < 4; ++i) v[i] = (g0 + i < NNODE) ? tmask[g0 + i] : 0;
    const int s = ((v[0] + v[1]) + (v[2] + v[3]));
    sp[t] = s;
    __syncthreads();
    for (int off = 1; off < 256; off <<= 1) {
        const int val = sp[t];
        const int add = (t >= off) ? sp[t - off] : 0;
        __syncthreads();
        sp[t] = val + add;
        __syncthreads();
    }
    int run = coff[c] + sp[t] - s;
#pragma unroll
    for (int i = 0; i < 4; ++i) {
        const int g = g0 + i;
        if (g < NNODE) {
            cmapx[g] = v[i] ? run : -1;
            if (v[i]) nodes[run] = g;
            if (g == USER_NUM) meta[1] = run;
            if (g % GROWS == 0) gslot[g / GROWS] = run;
            run += v[i];
        } else if (g == NNODE) {
            meta[0] = run;
            gslot[8] = run;
        }
    }
    if (g0 + 4 == NNODE) { meta[0] = run; gslot[8] = run; }
}

// Counts fill (N-domain, N multiple of 4): base + cursor; base[N]=total.
__global__ __launch_bounds__(256) void fill_kernel(const int* __restrict__ cnt,
                                                   const int* __restrict__ coff,
                                                   int* __restrict__ base,
                                                   int* __restrict__ cursor, int N) {
    __shared__ int sp[256];
    const int c  = blockIdx.x;
    const int t  = threadIdx.x;
    const int g0 = c * CHUNK + t * 4;
    int v[4];
#pragma unroll
    for (int i = 0; i < 4; ++i) v[i] = (g0 + i < N) ? cnt[g0 + i] : 0;
    const int s = ((v[0] + v[1]) + (v[2] + v[3]));
    sp[t] = s;
    __syncthreads();
    for (int off = 1; off < 256; off <<= 1) {
        const int val = sp[t];
        const int add = (t >= off) ? sp[t - off] : 0;
        __syncthreads();
        sp[t] = val + add;
        __syncthreads();
    }
    int run = coff[c] + sp[t] - s;
#pragma unroll
    for (int i = 0; i < 4; ++i) {
        const int g = g0 + i;
        if (g < N) {
            base[g]   = run;
            cursor[g] = run;
            run += v[i];
        }
    }
    if (g0 + 4 == N) base[N] = run;
}

// ---- Pass A: block-aggregated append of TOUCHED edges into 8 segments ------

__global__ __launch_bounds__(256) void append_kernel(
    const int* __restrict__ erow, const int* __restrict__ ecol,
    const float* __restrict__ eval, const int* __restrict__ cmapx,
    int* __restrict__ gcur, int* __restrict__ grow, int2* __restrict__ gpair,
    int E) {
    __shared__ int lcnt[8];
    __shared__ int lbase[8];
    const int t = threadIdx.x;
    if (t < 8) lcnt[t] = 0;
    __syncthreads();
    const int e0 = blockIdx.x * APB + t;
    int sl[EPT], c[EPT], gr[EPT], rk[EPT];
    float v[EPT];
#pragma unroll
    for (int i = 0; i < EPT; ++i) {
        const int e = e0 + 256 * i;
        gr[i] = -1;
        if (e < E) {
            const int r = erow[e];
            const int slot = cmapx[r];
            if (slot >= 0) {
                sl[i] = slot;
                c[i]  = ecol[e];
                v[i]  = eval[e];
                gr[i] = (r * 8) / NNODE;    // const div -> magic mul
                rk[i] = atomicAdd(&lcnt[gr[i]], 1);
            }
        }
    }
    __syncthreads();
    if (t < 8 && lcnt[t] > 0) lbase[t] = atomicAdd(&gcur[t], lcnt[t]);
    __syncthreads();
#pragma unroll
    for (int i = 0; i < EPT; ++i) {
        if (gr[i] >= 0) {
            const int pos = lbase[gr[i]] + rk[i];
            grow[pos]  = sl[i];             // compact slot
            gpair[pos] = make_int2(c[i], __float_as_int(v[i]));
        }
    }
}

// ---- Histogram: per-group LDS histogram over contiguous slot range ----------

__global__ __launch_bounds__(256) void hist3_kernel(const int* __restrict__ grow,
                                                    const int* __restrict__ gcur,
                                                    const int* __restrict__ gslot,
                                                    int* __restrict__ cnt2) {
    __shared__ int hloc[GROWS];
    const int g    = blockIdx.x & 7;
    const int rank = blockIdx.x >> 3;       // 0..NB3-1
    const int slo  = gslot[g];
    const int span = gslot[g + 1] - slo;
    for (int i = threadIdx.x; i < span; i += 256) hloc[i] = 0;
    __syncthreads();
    const int hi = gcur[g];
    for (int i = g * GCAP + rank * 256 + (int)threadIdx.x; i < hi; i += NB3 * 256)
        atomicAdd(&hloc[grow[i] - slo], 1);
    __syncthreads();
    for (int i = threadIdx.x; i < span; i += 256) {
        const int v = hloc[i];
        if (v) atomicAdd(&cnt2[slo + i], v);
    }
}

// ---- Pass B: per-group CSR scatter ------------------------------------------

__global__ __launch_bounds__(256) void scatter2_kernel(
    const int* __restrict__ grow, const int2* __restrict__ gpair,
    const int* __restrict__ gcur, int* __restrict__ cursor2,
    int2* __restrict__ epair) {
    const int g    = blockIdx.x & 7;
    const int rank = blockIdx.x >> 3;       // 0..NS2-1
    const int hi = gcur[g];
    for (int i = g * GCAP + rank * 256 + (int)threadIdx.x; i < hi; i += NS2 * 256) {
        const int slot = grow[i];
        const int pos = atomicAdd(&cursor2[slot], 1);
        epair[pos] = gpair[i];
    }
}

// ---- SpMM over compact touched rows ----------------------------------------

__global__ __launch_bounds__(256) void spmm_kernel(
    const float* __restrict__ ue, const float* __restrict__ ie,
    const int2* __restrict__ epair, const int* __restrict__ base2,
    const int* __restrict__ nodes, const int* __restrict__ meta,
    float* __restrict__ lx, float* __restrict__ lx2) {
    const int T = meta[0];
    const int lane = threadIdx.x & 63;
    int wv = (int)((blockIdx.x * blockDim.x + threadIdx.x) >> 6);
    wv = __builtin_amdgcn_readfirstlane(wv);
    const int nw = (int)((gridDim.x * blockDim.x) >> 6);
    for (int r = wv; r < T; r += nw) {
        const int jb = base2[r];
        const int je = base2[r + 1];
        float acc1 = 0.f, acc2 = 0.f;
        int j = jb;
        for (; j + 8 <= je; j += 8) {
            int2 p[8];
#pragma unroll
            for (int t = 0; t < 8; ++t) p[t] = epair[j + t];
            float f[8];
#pragma unroll
            for (int t = 0; t < 8; ++t) f[t] = feat_row(ue, ie, p[t].x)[lane];
#pragma unroll
            for (int t = 0; t < 8; ++t) {
                const float v = __int_as_float(p[t].y);
                acc1 = fmaf(v, f[t], acc1);
                acc2 = fmaf(v * f[t], f[t], acc2);
            }
        }
        for (; j + 4 <= je; j += 4) {
            int2 p[4];
#pragma unroll
            for (int t = 0; t < 4; ++t) p[t] = epair[j + t];
            float f[4];
#pragma unroll
            for (int t = 0; t < 4; ++t) f[t] = feat_row(ue, ie, p[t].x)[lane];
#pragma unroll
            for (int t = 0; t < 4; ++t) {
                const float v = __int_as_float(p[t].y);
                acc1 = fmaf(v, f[t], acc1);
                acc2 = fmaf(v * f[t], f[t], acc2);
            }
        }
        for (; j < je; ++j) {
            const int2 p = epair[j];
            const float f = feat_row(ue, ie, p.x)[lane];
            const float v = __int_as_float(p.y);
            acc1 = fmaf(v, f, acc1);
            acc2 = fmaf(v * f, f, acc2);
        }
        const int n = nodes[r];
        lx [(size_t)r * DD + lane] = acc1 + feat_row(ue, ie, n)[lane];
        lx2[(size_t)r * DD + lane] = acc2;
    }
}

// ---- Fused transform, combined user+item, 16-row tiles, 8 waves -------------
// blockIdx < nTilesU -> user tile; else item tile. Per tile:
//   phase1: h = lrelu(lx@Wg1 + lx2@Wg2 + bg1 + bg2)   -> kept in LDS
//   phase2: part = f@W1a + h@W1b (+ b1 for users)     -> global
// 512 threads = 8 waves = (khalf 2) x (row-quarter 4): 4 rows/wave/phase —
// halves the serial FMA-chain work per wave vs round-16's 4-wave layout.
// 12KB LDS, VGPR ~64 -> 4 blocks x 8 waves = 32 waves/CU possible.

__global__ __launch_bounds__(512) void xform_fused_kernel(
    const float* __restrict__ lx, const float* __restrict__ lx2,
    const float* __restrict__ ue, const float* __restrict__ ie,
    const float* __restrict__ Wg1, const float* __restrict__ Wg2,
    const float* __restrict__ bg1, const float* __restrict__ bg2,
    const float* __restrict__ W1, const float* __restrict__ b1,
    float* __restrict__ part,
    const int* __restrict__ nodes, const int* __restrict__ meta, int nTilesU) {
    const int Tu = meta[1];
    const int T  = meta[0];
    const bool isU   = (int)blockIdx.x < nTilesU;
    const int tileIx = isU ? blockIdx.x : (blockIdx.x - nTilesU);
    const int start  = isU ? 0  : Tu;
    const int lim    = isU ? Tu : T;
    const int tb     = start + tileIx * RT;
    if (tb >= lim) return;
    const float* fb = isU ? ue : ie;

    __shared__ float sXa[RT * DD];      // phase1: lx      phase2: h
    __shared__ float sXb[RT * DD];      // phase1: lx2     phase2: f
    __shared__ float sP [RT * DD];
    const int t     = threadIdx.x;
    const int lane  = t & 63;
    const int w     = t >> 6;           // 0..7
    const int khalf = (w & 1) * 32;
    const int rq    = (w >> 1) * (RT / 4);   // 4 rows per wave

    float wva[32], wvb[32];
#pragma unroll
    for (int k = 0; k < 32; ++k) {
        wva[k] = Wg1[(khalf + k) * DD + lane];
        wvb[k] = Wg2[(khalf + k) * DD + lane];
    }

    float4* sXav = (float4*)sXa;
    float4* sXbv = (float4*)sXb;
    float4* sPv  = (float4*)sP;
    // RT*DD/4 = 256 float4 slots, 512 threads -> first 256 threads stage
    if (t < RT * DD / 4) {
        const int f4  = t;
        const int row = f4 >> 4;
        const int c   = f4 & 15;
        const int g   = min(tb + row, lim - 1);
        sXav[f4] = ((const float4*)(lx  + (size_t)g * DD))[c];
        sXbv[f4] = ((const float4*)(lx2 + (size_t)g * DD))[c];
        sPv[f4]  = make_float4(0.f, 0.f, 0.f, 0.f);
    }
    __syncthreads();

    // phase 1: h partials
#pragma unroll
    for (int r = 0; r < RT / 4; ++r) {
        const int row = rq + r;
        const float* ra = &sXa[row * DD + khalf];
        const float* rb = &sXb[row * DD + khalf];
        float o0 = 0.f, o1 = 0.f, o2 = 0.f, o3 = 0.f;
#pragma unroll
        for (int q = 0; q < 8; ++q) {
            const float4 qa = *(const float4*)(ra + 4 * q);
            const float4 qb = *(const float4*)(rb + 4 * q);
            o0 = fmaf(qa.x, wva[4 * q + 0], o0);
            o1 = fmaf(qa.y, wva[4 * q + 1], o1);
            o0 = fmaf(qa.z, wva[4 * q + 2], o0);
            o1 = fmaf(qa.w, wva[4 * q + 3], o1);
            o2 = fmaf(qb.x, wvb[4 * q + 0], o2);
            o3 = fmaf(qb.y, wvb[4 * q + 1], o3);
            o2 = fmaf(qb.z, wvb[4 * q + 2], o2);
            o3 = fmaf(qb.w, wvb[4 * q + 3], o3);
        }
        atomicAdd(&sP[row * DD + lane], (o0 + o1) + (o2 + o3));
    }
    __syncthreads();

    // epilogue 1: h = lrelu(sP + bg1 + bg2) -> sXa; reset sP; stage f -> sXb
    if (t < RT * DD / 4) {
        const int f4  = t;
        const int row = f4 >> 4;
        const int c   = f4 & 15;
        float4 v = sPv[f4];
        const float4 ba = ((const float4*)bg1)[c];
        const float4 bb = ((const float4*)bg2)[c];
        v.x += ba.x + bb.x; v.y += ba.y + bb.y;
        v.z += ba.z + bb.z; v.w += ba.w + bb.w;
        v.x = (v.x > 0.f) ? v.x : 0.01f * v.x;
        v.y = (v.y > 0.f) ? v.y : 0.01f * v.y;
        v.z = (v.z > 0.f) ? v.z : 0.01f * v.z;
        v.w = (v.w > 0.f) ? v.w : 0.01f * v.w;
        sXav[f4] = v;                        // h
        sPv[f4]  = make_float4(0.f, 0.f, 0.f, 0.f);
        const int g = min(tb + row, lim - 1);
        int n = nodes[g];
        if (!isU) n -= USER_NUM;
        sXbv[f4] = ((const float4*)(fb + (size_t)n * DD))[c];   // f
    }

    // phase-2 weights: sXa(h) pairs W1b, sXb(f) pairs W1a
    const float* W1a = W1 + (isU ? 0 : 2 * DD * DD);
    const float* W1b = W1a + DD * DD;
#pragma unroll
    for (int k = 0; k < 32; ++k) {
        wva[k] = W1b[(khalf + k) * DD + lane];
        wvb[k] = W1a[(khalf + k) * DD + lane];
    }
    __syncthreads();

    // phase 2: part partials
#pragma unroll
    for (int r = 0; r < RT / 4; ++r) {
        const int row = rq + r;
        const float* ra = &sXa[row * DD + khalf];
        const float* rb = &sXb[row * DD + khalf];
        float o0 = 0.f, o1 = 0.f, o2 = 0.f, o3 = 0.f;
#pragma unroll
        for (int q = 0; q < 8; ++q) {
            const float4 qa = *(const float4*)(ra + 4 * q);
            const float4 qb = *(const float4*)(rb + 4 * q);
            o0 = fmaf(qa.x, wva[4 * q + 0], o0);
            o1 = fmaf(qa.y, wva[4 * q + 1], o1);
            o0 = fmaf(qa.z, wva[4 * q + 2], o0);
            o1 = fmaf(qa.w, wva[4 * q + 3], o1);
            o2 = fmaf(qb.x, wvb[4 * q + 0], o2);
            o3 = fmaf(qb.y, wvb[4 * q + 1], o3);
            o2 = fmaf(qb.z, wvb[4 * q + 2], o2);
            o3 = fmaf(qb.w, wvb[4 * q + 3], o3);
        }
        atomicAdd(&sP[row * DD + lane], (o0 + o1) + (o2 + o3));
    }
    __syncthreads();

    // epilogue 2: part = sP (+ b1 for users)
    float4* outv = (float4*)part;
    if (t < RT * DD / 4) {
        const int f4  = t;
        const int row = f4 >> 4;
        const int c   = f4 & 15;
        const int g   = tb + row;
        float4 v = sPv[f4];
        if (isU) {
            const float4 b = ((const float4*)b1)[c];
            v.x += b.x; v.y += b.y; v.z += b.z; v.w += b.w;
        }
        if (g < lim) outv[(size_t)g * 16 + c] = v;
    }
}

// ---- Per-sample MLP: o1 = relu(part_u + part_i); layers 2,3 ----------------

__global__ __launch_bounds__(256) void mlp_kernel(
    const float* __restrict__ part, const int* __restrict__ cmapx,
    const float* __restrict__ W2, const float* __restrict__ b2,
    const float* __restrict__ W3, const float* __restrict__ b3,
    const int* __restrict__ uid, const int* __restrict__ iid,
    float* __restrict__ out, int B) {
    __shared__ float sW2[DD * 32];
    __shared__ float sW3[32];
    for (int i = threadIdx.x; i < DD * 32; i += 256) sW2[i] = W2[i];
    if (threadIdx.x < 32) sW3[threadIdx.x] = W3[threadIdx.x];
    __syncthreads();
    const int lane = threadIdx.x & 63;
    const int wave = (int)((blockIdx.x * blockDim.x + threadIdx.x) >> 6);
    const int nw   = (int)((gridDim.x * blockDim.x) >> 6);
    const float bias2 = b2[lane & 31];
    const float w3v   = sW3[lane & 31];
    const float bias3 = b3[0];
    for (int s = wave; s < B; s += nw) {
        const int su = cmapx[uid[s]];
        const int si = cmapx[USER_NUM + iid[s]];
        const float pu = part[(size_t)su * DD + lane];
        const float pi = part[(size_t)si * DD + lane];
        const float x  = pu + pi;
        const float o1 = (x > 0.f) ? x : 0.f;
        float acc_a = bias2, acc_b = 0.f;
#pragma unroll
        for (int k = 0; k < DD; k += 2) {
            acc_a = fmaf(__shfl(o1, k),     sW2[k * 32 + (lane & 31)],       acc_a);
            acc_b = fmaf(__shfl(o1, k + 1), sW2[(k + 1) * 32 + (lane & 31)], acc_b);
        }
        const float a2 = acc_a + acc_b;
        const float o2 = (a2 > 0.f) ? a2 : 0.f;
        float p = o2 * w3v;
        p += __shfl_xor(p, 1);
        p += __shfl_xor(p, 2);
        p += __shfl_xor(p, 4);
        p += __shfl_xor(p, 8);
        p += __shfl_xor(p, 16);
        if (lane == 0) out[s] = p + bias3;
    }
}

extern "C" void kernel_launch(void* const* d_in, const int* in_sizes, int n_in,
                              void* d_out, int out_size, void* d_ws, size_t ws_size,
                              hipStream_t stream) {
    const float* ue   = (const float*)d_in[0];
    const float* ie   = (const float*)d_in[1];
    const int*   erow = (const int*)d_in[2];
    const int*   ecol = (const int*)d_in[3];
    const float* evalp= (const float*)d_in[4];
    const float* Wg1  = (const float*)d_in[5];
    const float* bg1  = (const float*)d_in[6];
    const float* Wg2  = (const float*)d_in[7];
    const float* bg2  = (const float*)d_in[8];
    const float* W1   = (const float*)d_in[9];
    const float* b1   = (const float*)d_in[10];
    const float* W2   = (const float*)d_in[11];
    const float* b2   = (const float*)d_in[12];
    const float* W3   = (const float*)d_in[13];
    const float* b3   = (const float*)d_in[14];
    const int*   uid  = (const int*)d_in[15];
    const int*   iid  = (const int*)d_in[16];
    float* out = (float*)d_out;

    const int E = in_sizes[2];
    const int B = in_sizes[15];

    const int TU_MAX = (B < USER_NUM) ? B : USER_NUM;   // touched users <= B
    const int TI_MAX = (B < ITEM_NUM) ? B : ITEM_NUM;   // touched items <= B
    const int nTilesU = (TU_MAX + RT - 1) / RT;
    const int nTilesI = (TI_MAX + RT - 1) / RT;

    // workspace layout (~49.5 MB peak):
    //  [A: 32MB  lx|lx2|part (8MB each, compact T_CAP rows) + 8MB spare]
    //    - during CSR build, grow(10.5MB)+gpair(21MB) overlay region A
    //      (both dead before spmm writes lx/lx2)
    //  [B: epair 16MB]
    //  [C: misc ints ~1.2MB]
    char* ws = (char*)d_ws;
    const size_t ndc = (size_t)T_CAP * DD;              // 8MB per array
    float* lx    = (float*)ws;
    float* lx2   = lx + ndc;
    float* part  = lx2 + ndc;
    int*   grow  = (int*)ws;                            // 8*GCAP ints (10.5MB)
    int2*  gpair = (int2*)(ws + 11u * 1024 * 1024);     // 8*GCAP int2 (21MB)
    char*  tail  = ws + 32u * 1024 * 1024;
    int2*  epair = (int2*)tail;                         // E int2 = 16MB
    int*   mi    = (int*)(tail + (size_t)E * sizeof(int2));
    int*   cnt2    = mi;                                // T_CAP
    int*   cursor2 = cnt2 + T_CAP;                      // T_CAP
    int*   base2   = cursor2 + T_CAP;                   // T_CAP+1
    int*   tmask   = base2 + T_CAP + 1;                 // NNODE
    int*   cmapx   = tmask + NNODE;                     // NNODE
    int*   nodes   = cmapx + NNODE;                     // T_CAP
    int*   csum    = nodes + T_CAP;                     // 128
    int*   coff    = csum + 128;                        // 128
    int*   gcur    = coff + 128;                        // 8
    int*   meta    = gcur + 8;                          // [0]=T, [1]=Tu
    int*   gslot   = meta + 8;                          // 9 ints

    zero_kernel<<<512, 256, 0, stream>>>(cnt2, tmask, gcur);
    mark_kernel<<<(B + 255) / 256, 256, 0, stream>>>(uid, iid, tmask, B);
    chunksum_kernel<<<NCHUNK, 256, 0, stream>>>(tmask, csum, NNODE);
    scan_small_kernel<<<1, 128, 0, stream>>>(csum, coff, NCHUNK);
    fill_flags_kernel<<<NCHUNK, 256, 0, stream>>>(tmask, coff, cmapx, nodes,
                                                  meta, gslot);
    append_kernel<<<(E + APB - 1) / APB, 256, 0, stream>>>(
        erow, ecol, evalp, cmapx, gcur, grow, gpair, E);
    hist3_kernel<<<8 * NB3, 256, 0, stream>>>(grow, gcur, gslot, cnt2);
    chunksum_kernel<<<NCHUNK2, 256, 0, stream>>>(cnt2, csum, T_CAP);
    scan_small_kernel<<<1, 128, 0, stream>>>(csum, coff, NCHUNK2);
    fill_kernel<<<NCHUNK2, 256, 0, stream>>>(cnt2, coff, base2, cursor2, T_CAP);
    scatter2_kernel<<<8 * NS2, 256, 0, stream>>>(grow, gpair, gcur, cursor2, epair);
    spmm_kernel<<<4096, 256, 0, stream>>>(ue, ie, epair, base2, nodes, meta,
                                          lx, lx2);

    // fused transform: one launch covers user + item tiles, 8 waves/block
    xform_fused_kernel<<<nTilesU + nTilesI, 512, 0, stream>>>(
        lx, lx2, ue, ie, Wg1, Wg2, bg1, bg2, W1, b1, part, nodes, meta, nTilesU);

    mlp_kernel<<<1024, 256, 0, stream>>>(part, cmapx, W2, b2, W3, b3,
                                         uid, iid, out, B);
}

// Round 20
// 197.442 us; speedup vs baseline: 1.3194x; 1.0337x over previous
//
#include <hip/hip_runtime.h>
#include <hip/hip_bf16.h>

#define USER_NUM 50000
#define ITEM_NUM 20000
#define NNODE    70000
#define DD       64
#define CHUNK    1024
#define NCHUNK   ((NNODE + CHUNK - 1) / CHUNK)   // 69
#define GROWS    (NNODE / 8)                     // 8750 rows per coarse group
#define APB      2048                            // append: edges per block
#define EPT      8                               // append: edges per thread
#define NS2      128                             // scatter2 stripes per group
#define NB3      16                              // hist3 blocks per group
#define T_CAP    32768                           // max touched slots (B=16384)
#define NCHUNK2  (T_CAP / CHUNK)                 // 32
#define GCAP     327680                          // per-group edge capacity
#define RT       16                              // xform tile rows (8KB LDS)

__device__ __forceinline__ const float* feat_row(const float* __restrict__ ue,
                                                 const float* __restrict__ ie, int n) {
    return (n < USER_NUM) ? (ue + (size_t)n * DD)
                          : (ie + (size_t)(n - USER_NUM) * DD);
}

// ---- init: zero cnt2/tmask, seed gcur --------------------------------------

__global__ __launch_bounds__(256) void zero_kernel(int* __restrict__ cnt2,
                                                   int* __restrict__ tmask,
                                                   int* __restrict__ gcur) {
    const int tid    = blockIdx.x * 256 + (int)threadIdx.x;
    const int stride = gridDim.x * 256;
    for (int i = tid; i < T_CAP; i += stride) cnt2[i] = 0;
    for (int i = tid; i < NNODE; i += stride) tmask[i] = 0;
    if (tid < 8) gcur[tid] = tid * GCAP;
}

// ---- Touched-node marking --------------------------------------------------

__global__ __launch_bounds__(256) void mark_kernel(const int* __restrict__ uid,
                                                   const int* __restrict__ iid,
                                                   int* __restrict__ tmask, int B) {
    const int stride = gridDim.x * blockDim.x;
    for (int s = blockIdx.x * blockDim.x + threadIdx.x; s < B; s += stride) {
        tmask[uid[s]] = 1;                       // racing same-value stores: benign
        tmask[USER_NUM + iid[s]] = 1;
    }
}

// ---- Generic 3-phase scan pieces (domain size N as arg) --------------------

__global__ __launch_bounds__(256) void chunksum_kernel(const int* __restrict__ arr,
                                                       int* __restrict__ csum, int N) {
    __shared__ int red[4];
    const int c = blockIdx.x;
    const int t = threadIdx.x;
    int s = 0;
#pragma unroll
    for (int i = 0; i < 4; ++i) {
        const int idx = c * CHUNK + t + 256 * i;
        s += (idx < N) ? arr[idx] : 0;
    }
#pragma unroll
    for (int off = 32; off; off >>= 1) s += __shfl_down(s, off);
    if ((t & 63) == 0) red[t >> 6] = s;
    __syncthreads();
    if (t == 0) csum[c] = red[0] + red[1] + red[2] + red[3];
}

__global__ __launch_bounds__(128) void scan_small_kernel(const int* __restrict__ csum,
                                                         int* __restrict__ coff,
                                                         int NC) {
    __shared__ int s[128];
    const int t = threadIdx.x;
    const int v = (t < NC) ? csum[t] : 0;
    s[t] = v;
    __syncthreads();
    for (int off = 1; off < 128; off <<= 1) {
        const int val = s[t];
        const int add = (t >= off) ? s[t - off] : 0;
        __syncthreads();
        s[t] = val + add;
        __syncthreads();
    }
    if (t < NC) coff[t] = s[t] - v;
}

// Flags fill (NNODE domain): cmapx (slot or -1), nodes, meta[0]=T, meta[1]=Tu,
// gslot[g] = first slot of node-range group g (g=0..8).
__global__ __launch_bounds__(256) void fill_flags_kernel(
    const int* __restrict__ tmask, const int* __restrict__ coff,
    int* __restrict__ cmapx, int* __restrict__ nodes, int* __restrict__ meta,
    int* __restrict__ gslot) {
    __shared__ int sp[256];
    const int c  = blockIdx.x;
    const int t  = threadIdx.x;
    const int g0 = c * CHUNK + t * 4;
    int v[4];
#pragma unroll
    for (int i = 0; i < 4; ++i) v[i] = (g0 + i < NNODE) ? tmask[g0 + i] : 0;
    const int s = ((v[0] + v[1]) + (v[2] + v[3]));
    sp[t] = s;
    __syncthreads();
    for (int off = 1; off < 256; off <<= 1) {
        const int val = sp[t];
        const int add = (t >= off) ? sp[t - off] : 0;
        __syncthreads();
        sp[t] = val + add;
        __syncthreads();
    }
    int run = coff[c] + sp[t] - s;
#pragma unroll
    for (int i = 0; i < 4; ++i) {
        const int g = g0 + i;
        if (g < NNODE) {
            cmapx[g] = v[i] ? run : -1;
            if (v[i]) nodes[run] = g;
            if (g == USER_NUM) meta[1] = run;
            if (g % GROWS == 0) gslot[g / GROWS] = run;
            run += v[i];
        } else if (g == NNODE) {
            meta[0] = run;
            gslot[8] = run;
        }
    }
    if (g0 + 4 == NNODE) { meta[0] = run; gslot[8] = run; }
}

// Counts fill (N-domain, N multiple of 4): base + cursor; base[N]=total.
__global__ __launch_bounds__(256) void fill_kernel(const int* __restrict__ cnt,
                                                   const int* __restrict__ coff,
                                                   int* __restrict__ base,
                                                   int* __restrict__ cursor, int N) {
    __shared__ int sp[256];
    const int c  = blockIdx.x;
    const int t  = threadIdx.x;
    const int g0 = c * CHUNK + t * 4;
    int v[4];
#pragma unroll
    for (int i = 0; i < 4; ++i) v[i] = (g0 + i < N) ? cnt[g0 + i] : 0;
    const int s = ((v[0] + v[1]) + (v[2] + v[3]));
    sp[t] = s;
    __syncthreads();
    for (int off = 1; off < 256; off <<= 1) {
        const int val = sp[t];
        const int add = (t >= off) ? sp[t - off] : 0;
        __syncthreads();
        sp[t] = val + add;
        __syncthreads();
    }
    int run = coff[c] + sp[t] - s;
#pragma unroll
    for (int i = 0; i < 4; ++i) {
        const int g = g0 + i;
        if (g < N) {
            base[g]   = run;
            cursor[g] = run;
            run += v[i];
        }
    }
    if (g0 + 4 == N) base[N] = run;
}

// ---- Pass A: block-aggregated append of TOUCHED edges into 8 segments ------

__global__ __launch_bounds__(256) void append_kernel(
    const int* __restrict__ erow, const int* __restrict__ ecol,
    const float* __restrict__ eval, const int* __restrict__ cmapx,
    int* __restrict__ gcur, int* __restrict__ grow, int2* __restrict__ gpair,
    int E) {
    __shared__ int lcnt[8];
    __shared__ int lbase[8];
    const int t = threadIdx.x;
    if (t < 8) lcnt[t] = 0;
    __syncthreads();
    const int e0 = blockIdx.x * APB + t;
    int sl[EPT], c[EPT], gr[EPT], rk[EPT];
    float v[EPT];
#pragma unroll
    for (int i = 0; i < EPT; ++i) {
        const int e = e0 + 256 * i;
        gr[i] = -1;
        if (e < E) {
            const int r = erow[e];
            const int slot = cmapx[r];
            if (slot >= 0) {
                sl[i] = slot;
                c[i]  = ecol[e];
                v[i]  = eval[e];
                gr[i] = (r * 8) / NNODE;    // const div -> magic mul
                rk[i] = atomicAdd(&lcnt[gr[i]], 1);
            }
        }
    }
    __syncthreads();
    if (t < 8 && lcnt[t] > 0) lbase[t] = atomicAdd(&gcur[t], lcnt[t]);
    __syncthreads();
#pragma unroll
    for (int i = 0; i < EPT; ++i) {
        if (gr[i] >= 0) {
            const int pos = lbase[gr[i]] + rk[i];
            grow[pos]  = sl[i];             // compact slot
            gpair[pos] = make_int2(c[i], __float_as_int(v[i]));
        }
    }
}

// ---- Histogram: per-group LDS histogram over contiguous slot range ----------

__global__ __launch_bounds__(256) void hist3_kernel(const int* __restrict__ grow,
                                                    const int* __restrict__ gcur,
                                                    const int* __restrict__ gslot,
                                                    int* __restrict__ cnt2) {
    __shared__ int hloc[GROWS];
    const int g    = blockIdx.x & 7;
    const int rank = blockIdx.x >> 3;       // 0..NB3-1
    const int slo  = gslot[g];
    const int span = gslot[g + 1] - slo;
    for (int i = threadIdx.x; i < span; i += 256) hloc[i] = 0;
    __syncthreads();
    const int hi = gcur[g];
    for (int i = g * GCAP + rank * 256 + (int)threadIdx.x; i < hi; i += NB3 * 256)
        atomicAdd(&hloc[grow[i] - slo], 1);
    __syncthreads();
    for (int i = threadIdx.x; i < span; i += 256) {
        const int v = hloc[i];
        if (v) atomicAdd(&cnt2[slo + i], v);
    }
}

// ---- Pass B: per-group CSR scatter ------------------------------------------

__global__ __launch_bounds__(256) void scatter2_kernel(
    const int* __restrict__ grow, const int2* __restrict__ gpair,
    const int* __restrict__ gcur, int* __restrict__ cursor2,
    int2* __restrict__ epair) {
    const int g    = blockIdx.x & 7;
    const int rank = blockIdx.x >> 3;       // 0..NS2-1
    const int hi = gcur[g];
    for (int i = g * GCAP + rank * 256 + (int)threadIdx.x; i < hi; i += NS2 * 256) {
        const int slot = grow[i];
        const int pos = atomicAdd(&cursor2[slot], 1);
        epair[pos] = gpair[i];
    }
}

// ---- SpMM over compact touched rows ----------------------------------------

__global__ __launch_bounds__(256) void spmm_kernel(
    const float* __restrict__ ue, const float* __restrict__ ie,
    const int2* __restrict__ epair, const int* __restrict__ base2,
    const int* __restrict__ nodes, const int* __restrict__ meta,
    float* __restrict__ lx, float* __restrict__ lx2) {
    const int T = meta[0];
    const int lane = threadIdx.x & 63;
    int wv = (int)((blockIdx.x * blockDim.x + threadIdx.x) >> 6);
    wv = __builtin_amdgcn_readfirstlane(wv);
    const int nw = (int)((gridDim.x * blockDim.x) >> 6);
    for (int r = wv; r < T; r += nw) {
        const int jb = base2[r];
        const int je = base2[r + 1];
        float acc1 = 0.f, acc2 = 0.f;
        int j = jb;
        for (; j + 8 <= je; j += 8) {
            int2 p[8];
#pragma unroll
            for (int t = 0; t < 8; ++t) p[t] = epair[j + t];
            float f[8];
#pragma unroll
            for (int t = 0; t < 8; ++t) f[t] = feat_row(ue, ie, p[t].x)[lane];
#pragma unroll
            for (int t = 0; t < 8; ++t) {
                const float v = __int_as_float(p[t].y);
                acc1 = fmaf(v, f[t], acc1);
                acc2 = fmaf(v * f[t], f[t], acc2);
            }
        }
        for (; j + 4 <= je; j += 4) {
            int2 p[4];
#pragma unroll
            for (int t = 0; t < 4; ++t) p[t] = epair[j + t];
            float f[4];
#pragma unroll
            for (int t = 0; t < 4; ++t) f[t] = feat_row(ue, ie, p[t].x)[lane];
#pragma unroll
            for (int t = 0; t < 4; ++t) {
                const float v = __int_as_float(p[t].y);
                acc1 = fmaf(v, f[t], acc1);
                acc2 = fmaf(v * f[t], f[t], acc2);
            }
        }
        for (; j < je; ++j) {
            const int2 p = epair[j];
            const float f = feat_row(ue, ie, p.x)[lane];
            const float v = __int_as_float(p.y);
            acc1 = fmaf(v, f, acc1);
            acc2 = fmaf(v * f, f, acc2);
        }
        const int n = nodes[r];
        lx [(size_t)r * DD + lane] = acc1 + feat_row(ue, ie, n)[lane];
        lx2[(size_t)r * DD + lane] = acc2;
    }
}

// ---- Fused transform, s_load activations -----------------------------------
// Per 16-row tile (4 waves = khalf 2 x rowhalf 2, 8 rows/wave/phase):
//   phase1: h = lrelu(lx@Wg1 + lx2@Wg2 + bg)   -> sH in LDS
//   phase2: part = f@W1a + h@W1b (+ b1 users)  -> global
// lx/lx2/f rows are WAVE-UNIFORM (readfirstlane-pinned) -> the compiler
// scalarizes them to s_load_dwordx16 on the SMEM pipe; each FMA is
// v_fma(acc, s_act, v_weight) — zero DS traffic for 3 of 4 operand streams.
// Only h (cross-lane by nature) is read via LDS broadcast. LDS 8KB.

__global__ __launch_bounds__(256) void xform_fused_kernel(
    const float* __restrict__ lx, const float* __restrict__ lx2,
    const float* __restrict__ ue, const float* __restrict__ ie,
    const float* __restrict__ Wg1, const float* __restrict__ Wg2,
    const float* __restrict__ bg1, const float* __restrict__ bg2,
    const float* __restrict__ W1, const float* __restrict__ b1,
    float* __restrict__ part,
    const int* __restrict__ nodes, const int* __restrict__ meta, int nTilesU) {
    const int Tu = meta[1];
    const int T  = meta[0];
    const bool isU   = (int)blockIdx.x < nTilesU;
    const int tileIx = isU ? blockIdx.x : (blockIdx.x - nTilesU);
    const int start  = isU ? 0  : Tu;
    const int lim    = isU ? Tu : T;
    const int tb     = start + tileIx * RT;
    if (tb >= lim) return;
    const float* fb = isU ? ue : ie;

    __shared__ float sH[RT * DD];
    __shared__ float sP[RT * DD];
    const int t     = threadIdx.x;
    const int lane  = t & 63;
    const int w     = t >> 6;
    const int khalf = (w & 1) * 32;
    const int rhalf = (w >> 1) * (RT / 2);

    float wva[32], wvb[32];
#pragma unroll
    for (int k = 0; k < 32; ++k) {
        wva[k] = Wg1[(khalf + k) * DD + lane];
        wvb[k] = Wg2[(khalf + k) * DD + lane];
    }

    float4* sHv = (float4*)sH;
    float4* sPv = (float4*)sP;
    sPv[t] = make_float4(0.f, 0.f, 0.f, 0.f);     // RT*DD/4 == 256 == blockDim
    __syncthreads();

    // phase 1: h partials; lx/lx2 via scalar loads
#pragma unroll 2
    for (int r = 0; r < RT / 2; ++r) {
        const int row = rhalf + r;
        int gc = min(tb + row, lim - 1);
        gc = __builtin_amdgcn_readfirstlane(gc);
        const float* xr = lx  + (size_t)gc * DD + khalf;
        const float* yr = lx2 + (size_t)gc * DD + khalf;
        float o0 = 0.f, o1 = 0.f, o2 = 0.f, o3 = 0.f;
#pragma unroll
        for (int q = 0; q < 8; ++q) {
            o0 = fmaf(xr[4 * q + 0], wva[4 * q + 0], o0);
            o1 = fmaf(xr[4 * q + 1], wva[4 * q + 1], o1);
            o0 = fmaf(xr[4 * q + 2], wva[4 * q + 2], o0);
            o1 = fmaf(xr[4 * q + 3], wva[4 * q + 3], o1);
            o2 = fmaf(yr[4 * q + 0], wvb[4 * q + 0], o2);
            o3 = fmaf(yr[4 * q + 1], wvb[4 * q + 1], o3);
            o2 = fmaf(yr[4 * q + 2], wvb[4 * q + 2], o2);
            o3 = fmaf(yr[4 * q + 3], wvb[4 * q + 3], o3);
        }
        atomicAdd(&sP[row * DD + lane], (o0 + o1) + (o2 + o3));
    }
    __syncthreads();

    // epilogue 1: h = lrelu(sP + bg1 + bg2) -> sH; reset sP
    {
        const int c = t & 15;
        float4 v = sPv[t];
        const float4 ba = ((const float4*)bg1)[c];
        const float4 bb = ((const float4*)bg2)[c];
        v.x += ba.x + bb.x; v.y += ba.y + bb.y;
        v.z += ba.z + bb.z; v.w += ba.w + bb.w;
        v.x = (v.x > 0.f) ? v.x : 0.01f * v.x;
        v.y = (v.y > 0.f) ? v.y : 0.01f * v.y;
        v.z = (v.z > 0.f) ? v.z : 0.01f * v.z;
        v.w = (v.w > 0.f) ? v.w : 0.01f * v.w;
        sHv[t] = v;
        sPv[t] = make_float4(0.f, 0.f, 0.f, 0.f);
    }

    // phase-2 weights: wva pairs h (W1b), wvb pairs f (W1a)
    const float* W1a = W1 + (isU ? 0 : 2 * DD * DD);
    const float* W1b = W1a + DD * DD;
#pragma unroll
    for (int k = 0; k < 32; ++k) {
        wva[k] = W1b[(khalf + k) * DD + lane];
        wvb[k] = W1a[(khalf + k) * DD + lane];
    }
    __syncthreads();

    // phase 2: part partials; f via scalar loads, h via LDS broadcast
#pragma unroll 2
    for (int r = 0; r < RT / 2; ++r) {
        const int row = rhalf + r;
        int gc = min(tb + row, lim - 1);
        gc = __builtin_amdgcn_readfirstlane(gc);
        int n = nodes[gc];
        if (!isU) n -= USER_NUM;
        n = __builtin_amdgcn_readfirstlane(n);
        const float* fr = fb + (size_t)n * DD + khalf;
        const float* hr = &sH[row * DD + khalf];
        float o0 = 0.f, o1 = 0.f, o2 = 0.f, o3 = 0.f;
#pragma unroll
        for (int q = 0; q < 8; ++q) {
            const float4 qh = *(const float4*)(hr + 4 * q);
            o0 = fmaf(qh.x, wva[4 * q + 0], o0);
            o1 = fmaf(qh.y, wva[4 * q + 1], o1);
            o0 = fmaf(qh.z, wva[4 * q + 2], o0);
            o1 = fmaf(qh.w, wva[4 * q + 3], o1);
            o2 = fmaf(fr[4 * q + 0], wvb[4 * q + 0], o2);
            o3 = fmaf(fr[4 * q + 1], wvb[4 * q + 1], o3);
            o2 = fmaf(fr[4 * q + 2], wvb[4 * q + 2], o2);
            o3 = fmaf(fr[4 * q + 3], wvb[4 * q + 3], o3);
        }
        atomicAdd(&sP[row * DD + lane], (o0 + o1) + (o2 + o3));
    }
    __syncthreads();

    // epilogue 2: part = sP (+ b1 for users)
    {
        const int row = t >> 4;
        const int c   = t & 15;
        const int g   = tb + row;
        float4 v = sPv[t];
        if (isU) {
            const float4 b = ((const float4*)b1)[c];
            v.x += b.x; v.y += b.y; v.z += b.z; v.w += b.w;
        }
        if (g < lim) ((float4*)part)[(size_t)g * 16 + c] = v;
    }
}

// ---- Per-sample MLP: o1 = relu(part_u + part_i); layers 2,3 ----------------

__global__ __launch_bounds__(256) void mlp_kernel(
    const float* __restrict__ part, const int* __restrict__ cmapx,
    const float* __restrict__ W2, const float* __restrict__ b2,
    const float* __restrict__ W3, const float* __restrict__ b3,
    const int* __restrict__ uid, const int* __restrict__ iid,
    float* __restrict__ out, int B) {
    __shared__ float sW2[DD * 32];
    __shared__ float sW3[32];
    for (int i = threadIdx.x; i < DD * 32; i += 256) sW2[i] = W2[i];
    if (threadIdx.x < 32) sW3[threadIdx.x] = W3[threadIdx.x];
    __syncthreads();
    const int lane = threadIdx.x & 63;
    const int wave = (int)((blockIdx.x * blockDim.x + threadIdx.x) >> 6);
    const int nw   = (int)((gridDim.x * blockDim.x) >> 6);
    const float bias2 = b2[lane & 31];
    const float w3v   = sW3[lane & 31];
    const float bias3 = b3[0];
    for (int s = wave; s < B; s += nw) {
        const int su = cmapx[uid[s]];
        const int si = cmapx[USER_NUM + iid[s]];
        const float pu = part[(size_t)su * DD + lane];
        const float pi = part[(size_t)si * DD + lane];
        const float x  = pu + pi;
        const float o1 = (x > 0.f) ? x : 0.f;
        float acc_a = bias2, acc_b = 0.f;
#pragma unroll
        for (int k = 0; k < DD; k += 2) {
            acc_a = fmaf(__shfl(o1, k),     sW2[k * 32 + (lane & 31)],       acc_a);
            acc_b = fmaf(__shfl(o1, k + 1), sW2[(k + 1) * 32 + (lane & 31)], acc_b);
        }
        const float a2 = acc_a + acc_b;
        const float o2 = (a2 > 0.f) ? a2 : 0.f;
        float p = o2 * w3v;
        p += __shfl_xor(p, 1);
        p += __shfl_xor(p, 2);
        p += __shfl_xor(p, 4);
        p += __shfl_xor(p, 8);
        p += __shfl_xor(p, 16);
        if (lane == 0) out[s] = p + bias3;
    }
}

extern "C" void kernel_launch(void* const* d_in, const int* in_sizes, int n_in,
                              void* d_out, int out_size, void* d_ws, size_t ws_size,
                              hipStream_t stream) {
    const float* ue   = (const float*)d_in[0];
    const float* ie   = (const float*)d_in[1];
    const int*   erow = (const int*)d_in[2];
    const int*   ecol = (const int*)d_in[3];
    const float* evalp= (const float*)d_in[4];
    const float* Wg1  = (const float*)d_in[5];
    const float* bg1  = (const float*)d_in[6];
    const float* Wg2  = (const float*)d_in[7];
    const float* bg2  = (const float*)d_in[8];
    const float* W1   = (const float*)d_in[9];
    const float* b1   = (const float*)d_in[10];
    const float* W2   = (const float*)d_in[11];
    const float* b2   = (const float*)d_in[12];
    const float* W3   = (const float*)d_in[13];
    const float* b3   = (const float*)d_in[14];
    const int*   uid  = (const int*)d_in[15];
    const int*   iid  = (const int*)d_in[16];
    float* out = (float*)d_out;

    const int E = in_sizes[2];
    const int B = in_sizes[15];

    const int TU_MAX = (B < USER_NUM) ? B : USER_NUM;   // touched users <= B
    const int TI_MAX = (B < ITEM_NUM) ? B : ITEM_NUM;   // touched items <= B
    const int nTilesU = (TU_MAX + RT - 1) / RT;
    const int nTilesI = (TI_MAX + RT - 1) / RT;

    // workspace layout (~49.5 MB peak):
    //  [A: 32MB  lx|lx2|part (8MB each, compact T_CAP rows) + 8MB spare]
    //    - during CSR build, grow(10.5MB)+gpair(21MB) overlay region A
    //      (both dead before spmm writes lx/lx2)
    //  [B: epair 16MB]
    //  [C: misc ints ~1.2MB]
    char* ws = (char*)d_ws;
    const size_t ndc = (size_t)T_CAP * DD;              // 8MB per array
    float* lx    = (float*)ws;
    float* lx2   = lx + ndc;
    float* part  = lx2 + ndc;
    int*   grow  = (int*)ws;                            // 8*GCAP ints (10.5MB)
    int2*  gpair = (int2*)(ws + 11u * 1024 * 1024);     // 8*GCAP int2 (21MB)
    char*  tail  = ws + 32u * 1024 * 1024;
    int2*  epair = (int2*)tail;                         // E int2 = 16MB
    int*   mi    = (int*)(tail + (size_t)E * sizeof(int2));
    int*   cnt2    = mi;                                // T_CAP
    int*   cursor2 = cnt2 + T_CAP;                      // T_CAP
    int*   base2   = cursor2 + T_CAP;                   // T_CAP+1
    int*   tmask   = base2 + T_CAP + 1;                 // NNODE
    int*   cmapx   = tmask + NNODE;                     // NNODE
    int*   nodes   = cmapx + NNODE;                     // T_CAP
    int*   csum    = nodes + T_CAP;                     // 128
    int*   coff    = csum + 128;                        // 128
    int*   gcur    = coff + 128;                        // 8
    int*   meta    = gcur + 8;                          // [0]=T, [1]=Tu
    int*   gslot   = meta + 8;                          // 9 ints

    zero_kernel<<<512, 256, 0, stream>>>(cnt2, tmask, gcur);
    mark_kernel<<<(B + 255) / 256, 256, 0, stream>>>(uid, iid, tmask, B);
    chunksum_kernel<<<NCHUNK, 256, 0, stream>>>(tmask, csum, NNODE);
    scan_small_kernel<<<1, 128, 0, stream>>>(csum, coff, NCHUNK);
    fill_flags_kernel<<<NCHUNK, 256, 0, stream>>>(tmask, coff, cmapx, nodes,
                                                  meta, gslot);
    append_kernel<<<(E + APB - 1) / APB, 256, 0, stream>>>(
        erow, ecol, evalp, cmapx, gcur, grow, gpair, E);
    hist3_kernel<<<8 * NB3, 256, 0, stream>>>(grow, gcur, gslot, cnt2);
    chunksum_kernel<<<NCHUNK2, 256, 0, stream>>>(cnt2, csum, T_CAP);
    scan_small_kernel<<<1, 128, 0, stream>>>(csum, coff, NCHUNK2);
    fill_kernel<<<NCHUNK2, 256, 0, stream>>>(cnt2, coff, base2, cursor2, T_CAP);
    scatter2_kernel<<<8 * NS2, 256, 0, stream>>>(grow, gpair, gcur, cursor2, epair);
    spmm_kernel<<<4096, 256, 0, stream>>>(ue, ie, epair, base2, nodes, meta,
                                          lx, lx2);

    // fused transform: s_load activations, one launch covers user+item tiles
    xform_fused_kernel<<<nTilesU + nTilesI, 256, 0, stream>>>(
        lx, lx2, ue, ie, Wg1, Wg2, bg1, bg2, W1, b1, part, nodes, meta, nTilesU);

    mlp_kernel<<<1024, 256, 0, stream>>>(part, cmapx, W2, b2, W3, b3,
                                         uid, iid, out, B);
}